// Round 6
// baseline (1162.817 us; speedup 1.0000x reference)
//
#include <hip/hip_runtime.h>

typedef unsigned short u16;
typedef __attribute__((ext_vector_type(8))) short short8;
typedef __attribute__((ext_vector_type(4))) float floatx4;

#define N_NODESC 100000
#define N_EDGESC 1600000
#define N_GRAPHSC 256
#define F_INC 128
#define HDIM 256
#define SCAN_CHUNK 512
#define SCAN_NB ((N_NODESC + SCAN_CHUNK - 1) / SCAN_CHUNK)  // 196
#define GEMM_BX 782
#define GEMM_NBLK (GEMM_BX * 2)

__device__ __forceinline__ float bf2f(u16 u) {
    union { unsigned int i; float f; } v; v.i = ((unsigned int)u) << 16; return v.f;
}
__device__ __forceinline__ u16 f2bf(float f) {
    union { float f; unsigned int i; } v; v.f = f;
    unsigned int b = v.i;
    b += 0x7fffu + ((b >> 16) & 1u);
    return (u16)(b >> 16);
}
__device__ __forceinline__ void up8(uint4 v, float* f) {
    f[0] = bf2f((u16)(v.x & 0xffff)); f[1] = bf2f((u16)(v.x >> 16));
    f[2] = bf2f((u16)(v.y & 0xffff)); f[3] = bf2f((u16)(v.y >> 16));
    f[4] = bf2f((u16)(v.z & 0xffff)); f[5] = bf2f((u16)(v.z >> 16));
    f[6] = bf2f((u16)(v.w & 0xffff)); f[7] = bf2f((u16)(v.w >> 16));
}
__device__ __forceinline__ unsigned int pk2(float a, float b) {
    return (unsigned int)f2bf(a) | ((unsigned int)f2bf(b) << 16);
}
// XCC_ID hwreg (id=20) — measured working on gfx950 (learn_hip m09)
__device__ __forceinline__ int get_xcd() {
    int x;
    asm volatile("s_getreg_b32 %0, hwreg(20, 0, 4)" : "=s"(x));
    return x & 7;
}

// ---------- weight prep: out[c*K + k] = (k<K1 ? Wl[k][c] : Wr[k-K1][c]) as bf16 ----------
__global__ void k_wcat(const float* __restrict__ Wl, const float* __restrict__ Wr,
                       int K1, int K2, u16* __restrict__ out) {
    int K = K1 + K2;
    int idx = blockIdx.x * 256 + threadIdx.x;
    if (idx >= 256 * K) return;
    int c = idx / K, k = idx - c * K;
    float v = (k < K1) ? Wl[k * 256 + c] : Wr[(k - K1) * 256 + c];
    out[idx] = f2bf(v);
}

// ---------- fp32 -> bf16 vectorized convert ----------
__global__ void k_f2bf4(const float* __restrict__ in, u16* __restrict__ out, int n4) {
    int i = blockIdx.x * 256 + threadIdx.x;
    if (i >= n4) return;
    float4 v = ((const float4*)in)[i];
    ushort4 o = make_ushort4(f2bf(v.x), f2bf(v.y), f2bf(v.z), f2bf(v.w));
    ((ushort4*)out)[i] = o;
}

// ---------- edge count: per-XCD partial histograms, XCD-local (workgroup-scope) atomics ----------
__global__ void k_countP(const int* __restrict__ dst, unsigned int* __restrict__ P,
                         unsigned int* __restrict__ epack, int E) {
    const int xcd = get_xcd();
    unsigned int* Px = P + (size_t)xcd * N_NODESC;
    const int e0 = blockIdx.x * 1024 + threadIdx.x;
#pragma unroll
    for (int l = 0; l < 4; ++l) {
        int e = e0 + l * 256;
        if (e < E) {
            int d = dst[e];
            unsigned int pos = __hip_atomic_fetch_add(&Px[d], 1u, __ATOMIC_RELAXED,
                                                      __HIP_MEMORY_SCOPE_WORKGROUP);
            epack[e] = ((unsigned int)xcd << 16) | pos;
        }
    }
}

// ---------- reduce partials: counts, 1/deg, per-(node,xcd) base offsets ----------
__global__ void k_reduceP(const unsigned int* __restrict__ P, int* __restrict__ counts,
                          float* __restrict__ dinv, u16* __restrict__ Bp, int n) {
    int d = blockIdx.x * 256 + threadIdx.x;
    if (d >= n) return;
    unsigned int s = 0;
    u16 b[8];
#pragma unroll
    for (int x = 0; x < 8; ++x) {
        b[x] = (u16)s;
        s += P[(size_t)x * n + d];
    }
    counts[d] = (int)s;
    dinv[d] = 1.0f / (float)(s > 1u ? s : 1u);
    ushort4* bp = (ushort4*)(Bp + (size_t)d * 8);
    bp[0] = make_ushort4(b[0], b[1], b[2], b[3]);
    bp[1] = make_ushort4(b[4], b[5], b[6], b[7]);
}

// ---------- 3-phase scan over counts -> csr_ptr ----------
__global__ void k_scan_bsum(const int* __restrict__ cnt, int* __restrict__ bsum, int n) {
    __shared__ int ts[256];
    int t = threadIdx.x;
    int i0 = blockIdx.x * SCAN_CHUNK + t * 2;
    int c0 = (i0 < n) ? cnt[i0] : 0;
    int c1 = (i0 + 1 < n) ? cnt[i0 + 1] : 0;
    ts[t] = c0 + c1;
    __syncthreads();
    for (int off = 128; off > 0; off >>= 1) {
        if (t < off) ts[t] += ts[t + off];
        __syncthreads();
    }
    if (t == 0) bsum[blockIdx.x] = ts[0];
}

__global__ void k_scan_boff(const int* __restrict__ bsum, int* __restrict__ boff, int nb) {
    __shared__ int ts[256];
    int t = threadIdx.x;
    int v = (t < nb) ? bsum[t] : 0;
    ts[t] = v;
    __syncthreads();
    for (int off = 1; off < 256; off <<= 1) {
        int u = (t >= off) ? ts[t - off] : 0;
        __syncthreads();
        ts[t] += u;
        __syncthreads();
    }
    if (t < nb) boff[t] = ts[t] - v;  // exclusive
}

__global__ void k_scan_write(const int* __restrict__ cnt, const int* __restrict__ boff,
                             int* __restrict__ cptr, int n) {
    __shared__ int ts[256];
    int t = threadIdx.x;
    int i0 = blockIdx.x * SCAN_CHUNK + t * 2;
    int c0 = (i0 < n) ? cnt[i0] : 0;
    int c1 = (i0 + 1 < n) ? cnt[i0 + 1] : 0;
    int ms = c0 + c1;
    ts[t] = ms;
    __syncthreads();
    for (int off = 1; off < 256; off <<= 1) {
        int u = (t >= off) ? ts[t - off] : 0;
        __syncthreads();
        ts[t] += u;
        __syncthreads();
    }
    int excl = ts[t] - ms + boff[blockIdx.x];
    if (i0 < n) cptr[i0] = excl;
    if (i0 + 1 < n) cptr[i0 + 1] = excl + c0;
    if (i0 == n - 1) cptr[n] = excl + c0;
    else if (i0 + 1 == n - 1) cptr[n] = excl + c0 + c1;
}

// ---------- CSR fill: slot fully determined, zero atomics ----------
__global__ void k_fill2(const int* __restrict__ src, const int* __restrict__ dst,
                        const unsigned int* __restrict__ epack,
                        const int* __restrict__ cptr, const u16* __restrict__ Bp,
                        int* __restrict__ adj, int E) {
    const int e0 = blockIdx.x * 1024 + threadIdx.x;
#pragma unroll
    for (int l = 0; l < 4; ++l) {
        int e = e0 + l * 256;
        if (e < E) {
            int d = dst[e];
            unsigned int pk = epack[e];
            int x = (int)(pk >> 16);
            int pos = (int)(pk & 0xFFFFu);
            adj[cptr[d] + (int)Bp[(size_t)d * 8 + x] + pos] = src[e];
        }
    }
}

// ---------- graph ranges: batch is sorted -> binary search lower bounds ----------
__global__ void k_gfind(const int* __restrict__ batch, int* __restrict__ gptr, int n) {
    int g = blockIdx.x * 64 + threadIdx.x;
    if (g > N_GRAPHSC) return;
    int lo = 0, hi = n;
    while (lo < hi) {
        int mid = (lo + hi) >> 1;
        if (batch[mid] < g) lo = mid + 1; else hi = mid;
    }
    gptr[g] = lo;
}

// ---------- aggregation v3: dwordx4 gathers, multiple rows per wave instruction ----------
// LPR lanes cover one row (16 B each); RPI = 64/LPR rows fetched per instruction.
// Accumulator: 8 fp32/lane over columns (lane%LPR)*8 .. +7; shfl_xor combine at end.
template <int F>
__global__ __launch_bounds__(256) void k_aggregate3(
    const u16* __restrict__ hin, const int* __restrict__ cptr,
    const int* __restrict__ adj, const float* __restrict__ di,
    u16* __restrict__ out, int n) {
    constexpr int LPR = F / 8;        // 16 (F=128) or 32 (F=256)
    constexpr int RPI = 64 / LPR;     // 4 or 2 rows per instruction
    const int lane = threadIdx.x & 63;
    const int node = blockIdx.x * 4 + (threadIdx.x >> 6);
    if (node >= n) return;
    const int sub = lane / LPR;       // which row-slot this lane serves
    const int li  = lane % LPR;       // 16B-chunk within the row
    const int p0 = cptr[node], p1 = cptr[node + 1];
    const float d = di[node];
    const u16* base = hin + (size_t)li * 8;
    float a[8];
#pragma unroll
    for (int e = 0; e < 8; ++e) a[e] = 0.f;

    int j = p0;
    while (j < p1) {
        int take = p1 - j; if (take > 64) take = 64;
        int myidx = (lane < take) ? adj[j + lane] : 0;
        const int ng = (take + RPI - 1) / RPI;
        for (int g0 = 0; g0 < ng; g0 += 4) {
            int sidx[4]; float m[4];
#pragma unroll
            for (int u = 0; u < 4; ++u) {
                int nb = (g0 + u) * RPI + sub;       // always <= 63 by construction
                sidx[u] = __shfl(myidx, nb & 63);
                m[u] = (nb < take) ? 1.f : 0.f;
            }
            uint4 hv[4];
#pragma unroll
            for (int u = 0; u < 4; ++u)
                hv[u] = *(const uint4*)(base + (size_t)sidx[u] * F);
#pragma unroll
            for (int u = 0; u < 4; ++u) {
                float f[8];
                up8(hv[u], f);
#pragma unroll
                for (int e = 0; e < 8; ++e) a[e] = fmaf(f[e], m[u], a[e]);
            }
        }
        j += take;
    }
    // combine the RPI row-slot partials
#pragma unroll
    for (int off = LPR; off < 64; off <<= 1)
#pragma unroll
        for (int e = 0; e < 8; ++e) a[e] += __shfl_xor(a[e], off);
    if (sub == 0) {
        uint4 o = make_uint4(pk2(a[0] * d, a[1] * d), pk2(a[2] * d, a[3] * d),
                             pk2(a[4] * d, a[5] * d), pk2(a[6] * d, a[7] * d));
        *(uint4*)(out + (size_t)node * F + li * 8) = o;
    }
}

// ---------- GEMM + fused column-stat partials ----------
__global__ __launch_bounds__(256) void k_gemm(
    const u16* __restrict__ A1, int K1,
    const u16* __restrict__ A2, int K2,
    const u16* __restrict__ Wt,
    u16* __restrict__ C, int M, float* __restrict__ statpart) {
    const int K = K1 + K2;
    __shared__ __align__(16) u16 Al[128 * 40];
    __shared__ __align__(16) u16 Bl[128 * 40];
    __shared__ float Ssum[2][128];
    __shared__ float Ssq[2][128];
    const int t = threadIdx.x;
    const int lane = t & 63;
    const int wave = t >> 6;
    const int wr = (wave >> 1) * 64, wc = (wave & 1) * 64;
    const int quad = lane >> 4, l15 = lane & 15;
    const int rowBase = blockIdx.x * 128;
    const int colBase = blockIdx.y * 128;

    floatx4 acc[4][4];
#pragma unroll
    for (int i = 0; i < 4; ++i)
#pragma unroll
        for (int j = 0; j < 4; ++j)
            acc[i][j] = (floatx4){0.f, 0.f, 0.f, 0.f};

    const int r0 = t >> 2;             // 0..63
    const int ch0 = (t & 3) * 8;       // 0,8,16,24 (elements)

    for (int kt = 0; kt < K; kt += 32) {
        const u16* As; int lda, kloc;
        if (kt < K1) { As = A1; lda = K1; kloc = kt; }
        else         { As = A2; lda = K2; kloc = kt - K1; }
#pragma unroll
        for (int l = 0; l < 2; ++l) {
            const int r = r0 + l * 64;
            const int grow = rowBase + r;
            uint4 va = make_uint4(0u, 0u, 0u, 0u);
            if (grow < M) va = *(const uint4*)(As + (size_t)grow * lda + (kloc + ch0));
            *(uint4*)(Al + r * 40 + ch0) = va;
            uint4 vb = *(const uint4*)(Wt + (size_t)(colBase + r) * K + (kt + ch0));
            *(uint4*)(Bl + r * 40 + ch0) = vb;
        }
        __syncthreads();
        short8 af[4], bfr[4];
#pragma unroll
        for (int i = 0; i < 4; ++i) af[i] = *(const short8*)(Al + (wr + i * 16 + l15) * 40 + quad * 8);
#pragma unroll
        for (int j = 0; j < 4; ++j) bfr[j] = *(const short8*)(Bl + (wc + j * 16 + l15) * 40 + quad * 8);
#pragma unroll
        for (int i = 0; i < 4; ++i)
#pragma unroll
            for (int j = 0; j < 4; ++j)
                acc[i][j] = __builtin_amdgcn_mfma_f32_16x16x32_bf16(af[i], bfr[j], acc[i][j], 0, 0, 0);
        __syncthreads();
    }
    // fused column stats (pad rows have zero A -> zero acc, contribute nothing)
    if (statpart) {
#pragma unroll
        for (int j = 0; j < 4; ++j) {
            float s = 0.f, q = 0.f;
#pragma unroll
            for (int i = 0; i < 4; ++i)
#pragma unroll
                for (int r = 0; r < 4; ++r) {
                    float v = acc[i][j][r];
                    s += v; q += v * v;
                }
            s += __shfl_down(s, 32); s += __shfl_down(s, 16);
            q += __shfl_down(q, 32); q += __shfl_down(q, 16);
            if (lane < 16) {
                Ssum[wr >> 6][wc + j * 16 + l15] = s;
                Ssq[wr >> 6][wc + j * 16 + l15] = q;
            }
        }
        __syncthreads();
        if (t < 128) {
            const size_t bid = (size_t)blockIdx.y * GEMM_BX + blockIdx.x;
            statpart[bid * 256 + t] = Ssum[0][t] + Ssum[1][t];
            statpart[bid * 256 + 128 + t] = Ssq[0][t] + Ssq[1][t];
        }
    }
#pragma unroll
    for (int i = 0; i < 4; ++i) {
#pragma unroll
        for (int r = 0; r < 4; ++r) {
            const int row = rowBase + wr + i * 16 + quad * 4 + r;
            if (row < M) {
#pragma unroll
                for (int j = 0; j < 4; ++j) {
                    const int col = colBase + wc + j * 16 + l15;
                    C[(size_t)row * HDIM + col] = f2bf(acc[i][j][r]);
                }
            }
        }
    }
}

// ---------- fused stat reduce + BN scale/shift: one block per column ----------
__global__ void k_statbn(const float* __restrict__ sp, const float* __restrict__ g,
                         const float* __restrict__ beta, float* __restrict__ sc,
                         float* __restrict__ sh, float invN) {
    const int c = blockIdx.x;                        // 0..255
    const size_t base = (size_t)(c >> 7) * GEMM_BX;  // which column-tile
    const int off = c & 127;
    float s = 0.f, q = 0.f;
    for (int bx = threadIdx.x; bx < GEMM_BX; bx += 64) {
        s += sp[(base + bx) * 256 + off];
        q += sp[(base + bx) * 256 + 128 + off];
    }
#pragma unroll
    for (int o = 32; o > 0; o >>= 1) { s += __shfl_down(s, o); q += __shfl_down(q, o); }
    if (threadIdx.x == 0) {
        float mu = s * invN;
        float var = q * invN - mu * mu;
        float k = g[c] * rsqrtf(var + 1e-5f);
        sc[c] = k;
        sh[c] = beta[c] - mu * k;
    }
}

// ---------- h_next = relu(C*scale+shift) + identity (+res_b); optional fused dot ----------
__global__ __launch_bounds__(256) void k_finalize2(
    const u16* __restrict__ Cb, const u16* __restrict__ iden,
    const float* __restrict__ sc, const float* __restrict__ sh,
    const float* __restrict__ resb, const float* __restrict__ w,
    u16* __restrict__ hout, float* __restrict__ nodedot) {
    const int i = blockIdx.x * 256 + threadIdx.x;   // tile id, 32 elems each; grid exact
    const size_t base = (size_t)i * 32;
    const int c0 = (i & 7) * 32;                    // column base within row
    const uint4* cp = (const uint4*)(Cb + base);
    const uint4* ip = (const uint4*)(iden + base);
    uint4 cv[4], iv[4];
#pragma unroll
    for (int q = 0; q < 4; ++q) cv[q] = cp[q];
#pragma unroll
    for (int q = 0; q < 4; ++q) iv[q] = ip[q];

    float dot = 0.f;
    uint4* op = (uint4*)(hout + base);
#pragma unroll
    for (int q = 0; q < 4; ++q) {
        float cf[8], df[8];
        up8(cv[q], cf); up8(iv[q], df);
        const float4 s0 = ((const float4*)(sc + c0 + q * 8))[0];
        const float4 s1 = ((const float4*)(sc + c0 + q * 8))[1];
        const float4 h0 = ((const float4*)(sh + c0 + q * 8))[0];
        const float4 h1 = ((const float4*)(sh + c0 + q * 8))[1];
        float scf[8] = {s0.x, s0.y, s0.z, s0.w, s1.x, s1.y, s1.z, s1.w};
        float shf[8] = {h0.x, h0.y, h0.z, h0.w, h1.x, h1.y, h1.z, h1.w};
        float rbf[8] = {0.f, 0.f, 0.f, 0.f, 0.f, 0.f, 0.f, 0.f};
        if (resb) {
            const float4 r0 = ((const float4*)(resb + c0 + q * 8))[0];
            const float4 r1 = ((const float4*)(resb + c0 + q * 8))[1];
            rbf[0] = r0.x; rbf[1] = r0.y; rbf[2] = r0.z; rbf[3] = r0.w;
            rbf[4] = r1.x; rbf[5] = r1.y; rbf[6] = r1.z; rbf[7] = r1.w;
        }
        float o[8];
#pragma unroll
        for (int e = 0; e < 8; ++e) {
            float v = cf[e] * scf[e] + shf[e];
            o[e] = fmaxf(v, 0.f) + df[e] + rbf[e];
        }
        if (nodedot) {
            const float4 w0 = ((const float4*)(w + c0 + q * 8))[0];
            const float4 w1 = ((const float4*)(w + c0 + q * 8))[1];
            dot += o[0] * w0.x + o[1] * w0.y + o[2] * w0.z + o[3] * w0.w
                 + o[4] * w1.x + o[5] * w1.y + o[6] * w1.z + o[7] * w1.w;
        }
        op[q] = make_uint4(pk2(o[0], o[1]), pk2(o[2], o[3]), pk2(o[4], o[5]), pk2(o[6], o[7]));
    }
    if (nodedot) {
        dot += __shfl_down(dot, 4);
        dot += __shfl_down(dot, 2);
        dot += __shfl_down(dot, 1);
        if ((threadIdx.x & 7) == 0) nodedot[i >> 3] = dot;
    }
}

// ---------- readout stage 2: one block per graph, contiguous segment sum ----------
__global__ void k_pool(const float* __restrict__ nodedot, const int* __restrict__ gptr,
                       const float* __restrict__ lb, float* __restrict__ out) {
    const int g = blockIdx.x;
    const int r0 = gptr[g], r1 = gptr[g + 1];
    float s = 0.f;
    for (int i = r0 + threadIdx.x; i < r1; i += 256) s += nodedot[i];
#pragma unroll
    for (int off = 32; off > 0; off >>= 1) s += __shfl_down(s, off);
    __shared__ float red[4];
    const int wave = threadIdx.x >> 6;
    if ((threadIdx.x & 63) == 0) red[wave] = s;
    __syncthreads();
    if (threadIdx.x == 0) {
        float tot = red[0] + red[1] + red[2] + red[3];
        int c = r1 - r0; if (c < 1) c = 1;
        out[g] = tot / (float)c + lb[0];
    }
}

extern "C" void kernel_launch(void* const* d_in, const int* in_sizes, int n_in,
                              void* d_out, int out_size, void* d_ws, size_t ws_size,
                              hipStream_t stream) {
    const float* x     = (const float*)d_in[0];
    const int*   ei    = (const int*)d_in[1];
    const int*   batch = (const int*)d_in[2];
    const float* Wl1 = (const float*)d_in[3];
    const float* Wr1 = (const float*)d_in[5];
    const float* g1  = (const float*)d_in[6];
    const float* be1 = (const float*)d_in[7];
    const float* Wl2 = (const float*)d_in[8];
    const float* Wr2 = (const float*)d_in[10];
    const float* g2  = (const float*)d_in[11];
    const float* be2 = (const float*)d_in[12];
    const float* Wl3 = (const float*)d_in[13];
    const float* Wr3 = (const float*)d_in[15];
    const float* g3  = (const float*)d_in[16];
    const float* be3 = (const float*)d_in[17];
    const float* Wl4 = (const float*)d_in[18];
    const float* Wr4 = (const float*)d_in[20];
    const float* g4  = (const float*)d_in[21];
    const float* be4 = (const float*)d_in[22];
    const float* resW = (const float*)d_in[23];
    const float* resb = (const float*)d_in[24];
    const float* linW = (const float*)d_in[25];
    const float* linb = (const float*)d_in[26];
    float* out = (float*)d_out;

    char* p = (char*)d_ws;
    auto carve = [&](size_t bytes) -> char* {
        char* r = p;
        p += (bytes + 255) & ~(size_t)255;
        return r;
    };
    int*   cptr    = (int*)carve((size_t)(N_NODESC + 1) * 4);
    int*   counts  = (int*)carve((size_t)N_NODESC * 4);
    float* dinv    = (float*)carve((size_t)N_NODESC * 4);
    int*   gptr    = (int*)carve((N_GRAPHSC + 1) * 4);
    float* nodedot = (float*)carve((size_t)N_NODESC * 4);
    float* statpart= (float*)carve((size_t)GEMM_NBLK * 256 * 4);
    float* scale   = (float*)carve(256 * 4);
    float* shift   = (float*)carve(256 * 4);
    int*   bsum    = (int*)carve(SCAN_NB * 4);
    int*   boff    = (int*)carve(SCAN_NB * 4);
    int*   adj     = (int*)carve((size_t)N_EDGESC * 4);
    u16*   Wt1     = (u16*)carve(256 * 256 * 2);
    u16*   Wt2     = (u16*)carve(256 * 512 * 2);
    u16*   Wt3     = (u16*)carve(256 * 512 * 2);
    u16*   Wt4     = (u16*)carve(256 * 512 * 2);
    u16*   Rt      = (u16*)carve(256 * 128 * 2);
    u16*   xb      = (u16*)carve((size_t)N_NODESC * F_INC * 2);
    u16*   hA      = (u16*)carve((size_t)N_NODESC * HDIM * 2);
    u16*   hB      = (u16*)carve((size_t)N_NODESC * HDIM * 2);
    u16*   agg     = (u16*)carve((size_t)N_NODESC * HDIM * 2);  // aliased as res for layer 1
    u16*   Cb      = (u16*)carve((size_t)N_NODESC * HDIM * 2);

    // CSR-build temporaries alias big buffers that are dead during the build:
    unsigned int* P     = (unsigned int*)hA;  // 3.2 MB; dead before hA written (layer-1 finalize)
    unsigned int* epack = (unsigned int*)Cb;  // 6.4 MB; dead before Cb written (layer-1 gemm)
    u16*          Bp    = (u16*)hB;           // 1.6 MB; dead before hB written (layer-2 finalize)

    hipMemsetAsync(P, 0, (size_t)8 * N_NODESC * 4, stream);

    const int* srcp = ei;
    const int* dstp = ei + N_EDGESC;

    // weight prep + x conversion
    k_wcat<<<(256 * 256 + 255) / 256, 256, 0, stream>>>(Wl1, Wr1, 128, 128, Wt1);
    k_wcat<<<(256 * 512 + 255) / 256, 256, 0, stream>>>(Wl2, Wr2, 256, 256, Wt2);
    k_wcat<<<(256 * 512 + 255) / 256, 256, 0, stream>>>(Wl3, Wr3, 256, 256, Wt3);
    k_wcat<<<(256 * 512 + 255) / 256, 256, 0, stream>>>(Wl4, Wr4, 256, 256, Wt4);
    k_wcat<<<(256 * 128 + 255) / 256, 256, 0, stream>>>(resW, resW, 128, 0, Rt);
    k_f2bf4<<<(N_NODESC * F_INC / 4 + 255) / 256, 256, 0, stream>>>(x, xb, N_NODESC * F_INC / 4);

    // graph structure (no device-scope atomics anywhere)
    k_gfind<<<5, 64, 0, stream>>>(batch, gptr, N_NODESC);
    k_countP<<<(N_EDGESC + 1023) / 1024, 256, 0, stream>>>(dstp, P, epack, N_EDGESC);
    k_reduceP<<<(N_NODESC + 255) / 256, 256, 0, stream>>>(P, counts, dinv, Bp, N_NODESC);
    k_scan_bsum<<<SCAN_NB, 256, 0, stream>>>(counts, bsum, N_NODESC);
    k_scan_boff<<<1, 256, 0, stream>>>(bsum, boff, SCAN_NB);
    k_scan_write<<<SCAN_NB, 256, 0, stream>>>(counts, boff, cptr, N_NODESC);
    k_fill2<<<(N_EDGESC + 1023) / 1024, 256, 0, stream>>>(srcp, dstp, epack, cptr, Bp, adj, N_EDGESC);

    dim3 gGemm(GEMM_BX, 2);
    const float invN = 1.0f / (float)N_NODESC;
    const int finBlocks = N_NODESC * HDIM / 32 / 256;  // 3125, exact

    // ---- layer 1 ----
    k_aggregate3<128><<<25000, 256, 0, stream>>>(xb, cptr, adj, dinv, agg, N_NODESC);
    k_gemm<<<gGemm, 256, 0, stream>>>(agg, 128, xb, 128, Wt1, Cb, N_NODESC, statpart);
    k_gemm<<<gGemm, 256, 0, stream>>>(xb, 128, xb, 0, Rt, agg, N_NODESC, nullptr);  // res reuses agg
    k_statbn<<<256, 64, 0, stream>>>(statpart, g1, be1, scale, shift, invN);
    k_finalize2<<<finBlocks, 256, 0, stream>>>(Cb, agg, scale, shift, resb, nullptr, hA, nullptr);

    // ---- layer 2 ----
    k_aggregate3<256><<<25000, 256, 0, stream>>>(hA, cptr, adj, dinv, agg, N_NODESC);
    k_gemm<<<gGemm, 256, 0, stream>>>(agg, 256, hA, 256, Wt2, Cb, N_NODESC, statpart);
    k_statbn<<<256, 64, 0, stream>>>(statpart, g2, be2, scale, shift, invN);
    k_finalize2<<<finBlocks, 256, 0, stream>>>(Cb, hA, scale, shift, nullptr, nullptr, hB, nullptr);

    // ---- layer 3 ----
    k_aggregate3<256><<<25000, 256, 0, stream>>>(hB, cptr, adj, dinv, agg, N_NODESC);
    k_gemm<<<gGemm, 256, 0, stream>>>(agg, 256, hB, 256, Wt3, Cb, N_NODESC, statpart);
    k_statbn<<<256, 64, 0, stream>>>(statpart, g3, be3, scale, shift, invN);
    k_finalize2<<<finBlocks, 256, 0, stream>>>(Cb, hB, scale, shift, nullptr, nullptr, hA, nullptr);

    // ---- layer 4 (fused per-node dot with lin_W) ----
    k_aggregate3<256><<<25000, 256, 0, stream>>>(hA, cptr, adj, dinv, agg, N_NODESC);
    k_gemm<<<gGemm, 256, 0, stream>>>(agg, 256, hA, 256, Wt4, Cb, N_NODESC, statpart);
    k_statbn<<<256, 64, 0, stream>>>(statpart, g4, be4, scale, shift, invN);
    k_finalize2<<<finBlocks, 256, 0, stream>>>(Cb, hA, scale, shift, nullptr, linW, hB, nodedot);

    // ---- pooled mean + lin_b ----
    k_pool<<<N_GRAPHSC, 256, 0, stream>>>(nodedot, gptr, linb, out);
}

// Round 7
// 1016.812 us; speedup vs baseline: 1.1436x; 1.1436x over previous
//
#include <hip/hip_runtime.h>

typedef unsigned short u16;
typedef __attribute__((ext_vector_type(8))) short short8;
typedef __attribute__((ext_vector_type(4))) float floatx4;
typedef __attribute__((ext_vector_type(2))) float floatx2;

#define N_NODESC 100000
#define N_EDGESC 1600000
#define N_GRAPHSC 256
#define F_INC 128
#define HDIM 256
#define SCAN_CHUNK 512
#define SCAN_NB ((N_NODESC + SCAN_CHUNK - 1) / SCAN_CHUNK)  // 196
#define GEMM_BX 782
#define GEMM_NBLK (GEMM_BX * 2)

__device__ __forceinline__ float bf2f(u16 u) {
    union { unsigned int i; float f; } v; v.i = ((unsigned int)u) << 16; return v.f;
}
__device__ __forceinline__ u16 f2bf(float f) {
    union { float f; unsigned int i; } v; v.f = f;
    unsigned int b = v.i;
    b += 0x7fffu + ((b >> 16) & 1u);
    return (u16)(b >> 16);
}
__device__ __forceinline__ void up8(uint4 v, float* f) {
    f[0] = bf2f((u16)(v.x & 0xffff)); f[1] = bf2f((u16)(v.x >> 16));
    f[2] = bf2f((u16)(v.y & 0xffff)); f[3] = bf2f((u16)(v.y >> 16));
    f[4] = bf2f((u16)(v.z & 0xffff)); f[5] = bf2f((u16)(v.z >> 16));
    f[6] = bf2f((u16)(v.w & 0xffff)); f[7] = bf2f((u16)(v.w >> 16));
}
__device__ __forceinline__ unsigned int pk2(float a, float b) {
    return (unsigned int)f2bf(a) | ((unsigned int)f2bf(b) << 16);
}
// decode 16 fp8(e4m3) from uint4 -> 16 floats (HW v_cvt_pk_f32_fp8, OCP on gfx950)
__device__ __forceinline__ void dq16(uint4 v, float* f) {
    floatx2 p;
    p = __builtin_amdgcn_cvt_pk_f32_fp8(v.x, false); f[0] = p[0]; f[1] = p[1];
    p = __builtin_amdgcn_cvt_pk_f32_fp8(v.x, true);  f[2] = p[0]; f[3] = p[1];
    p = __builtin_amdgcn_cvt_pk_f32_fp8(v.y, false); f[4] = p[0]; f[5] = p[1];
    p = __builtin_amdgcn_cvt_pk_f32_fp8(v.y, true);  f[6] = p[0]; f[7] = p[1];
    p = __builtin_amdgcn_cvt_pk_f32_fp8(v.z, false); f[8] = p[0]; f[9] = p[1];
    p = __builtin_amdgcn_cvt_pk_f32_fp8(v.z, true);  f[10] = p[0]; f[11] = p[1];
    p = __builtin_amdgcn_cvt_pk_f32_fp8(v.w, false); f[12] = p[0]; f[13] = p[1];
    p = __builtin_amdgcn_cvt_pk_f32_fp8(v.w, true);  f[14] = p[0]; f[15] = p[1];
}
// XCC_ID hwreg (id=20) — measured working on gfx950 (learn_hip m09)
__device__ __forceinline__ int get_xcd() {
    int x;
    asm volatile("s_getreg_b32 %0, hwreg(20, 0, 4)" : "=s"(x));
    return x & 7;
}

// ---------- weight prep: out[c*K + k] = (k<K1 ? Wl[k][c] : Wr[k-K1][c]) as bf16 ----------
__global__ void k_wcat(const float* __restrict__ Wl, const float* __restrict__ Wr,
                       int K1, int K2, u16* __restrict__ out) {
    int K = K1 + K2;
    int idx = blockIdx.x * 256 + threadIdx.x;
    if (idx >= 256 * K) return;
    int c = idx / K, k = idx - c * K;
    float v = (k < K1) ? Wl[k * 256 + c] : Wr[(k - K1) * 256 + c];
    out[idx] = f2bf(v);
}

// ---------- fp32 -> bf16 + fp8 dual convert (8 elems/thread) ----------
__global__ void k_f2both(const float* __restrict__ in, u16* __restrict__ outb,
                         unsigned char* __restrict__ out8, int n8) {
    int i = blockIdx.x * 256 + threadIdx.x;
    if (i >= n8) return;
    float4 v0 = ((const float4*)in)[2 * i];
    float4 v1 = ((const float4*)in)[2 * i + 1];
    ((uint4*)outb)[i] = make_uint4(pk2(v0.x, v0.y), pk2(v0.z, v0.w),
                                   pk2(v1.x, v1.y), pk2(v1.z, v1.w));
    unsigned int wlo = __builtin_amdgcn_cvt_pk_fp8_f32(v0.x, v0.y, 0, false);
    wlo = __builtin_amdgcn_cvt_pk_fp8_f32(v0.z, v0.w, wlo, true);
    unsigned int whi = __builtin_amdgcn_cvt_pk_fp8_f32(v1.x, v1.y, 0, false);
    whi = __builtin_amdgcn_cvt_pk_fp8_f32(v1.z, v1.w, whi, true);
    ((uint2*)out8)[i] = make_uint2(wlo, whi);
}

// ---------- edge count: per-XCD partial histograms, XCD-local (workgroup-scope) atomics ----------
__global__ void k_countP(const int* __restrict__ dst, unsigned int* __restrict__ P,
                         unsigned int* __restrict__ epack, int E) {
    const int xcd = get_xcd();
    unsigned int* Px = P + (size_t)xcd * N_NODESC;
    const int e0 = blockIdx.x * 1024 + threadIdx.x;
#pragma unroll
    for (int l = 0; l < 4; ++l) {
        int e = e0 + l * 256;
        if (e < E) {
            int d = dst[e];
            unsigned int pos = __hip_atomic_fetch_add(&Px[d], 1u, __ATOMIC_RELAXED,
                                                      __HIP_MEMORY_SCOPE_WORKGROUP);
            epack[e] = ((unsigned int)xcd << 16) | pos;
        }
    }
}

// ---------- reduce partials: counts, 1/deg, per-(node,xcd) base offsets ----------
__global__ void k_reduceP(const unsigned int* __restrict__ P, int* __restrict__ counts,
                          float* __restrict__ dinv, u16* __restrict__ Bp, int n) {
    int d = blockIdx.x * 256 + threadIdx.x;
    if (d >= n) return;
    unsigned int s = 0;
    u16 b[8];
#pragma unroll
    for (int x = 0; x < 8; ++x) {
        b[x] = (u16)s;
        s += P[(size_t)x * n + d];
    }
    counts[d] = (int)s;
    dinv[d] = 1.0f / (float)(s > 1u ? s : 1u);
    ushort4* bp = (ushort4*)(Bp + (size_t)d * 8);
    bp[0] = make_ushort4(b[0], b[1], b[2], b[3]);
    bp[1] = make_ushort4(b[4], b[5], b[6], b[7]);
}

// ---------- 3-phase scan over counts -> csr_ptr ----------
__global__ void k_scan_bsum(const int* __restrict__ cnt, int* __restrict__ bsum, int n) {
    __shared__ int ts[256];
    int t = threadIdx.x;
    int i0 = blockIdx.x * SCAN_CHUNK + t * 2;
    int c0 = (i0 < n) ? cnt[i0] : 0;
    int c1 = (i0 + 1 < n) ? cnt[i0 + 1] : 0;
    ts[t] = c0 + c1;
    __syncthreads();
    for (int off = 128; off > 0; off >>= 1) {
        if (t < off) ts[t] += ts[t + off];
        __syncthreads();
    }
    if (t == 0) bsum[blockIdx.x] = ts[0];
}

__global__ void k_scan_boff(const int* __restrict__ bsum, int* __restrict__ boff, int nb) {
    __shared__ int ts[256];
    int t = threadIdx.x;
    int v = (t < nb) ? bsum[t] : 0;
    ts[t] = v;
    __syncthreads();
    for (int off = 1; off < 256; off <<= 1) {
        int u = (t >= off) ? ts[t - off] : 0;
        __syncthreads();
        ts[t] += u;
        __syncthreads();
    }
    if (t < nb) boff[t] = ts[t] - v;  // exclusive
}

__global__ void k_scan_write(const int* __restrict__ cnt, const int* __restrict__ boff,
                             int* __restrict__ cptr, int n) {
    __shared__ int ts[256];
    int t = threadIdx.x;
    int i0 = blockIdx.x * SCAN_CHUNK + t * 2;
    int c0 = (i0 < n) ? cnt[i0] : 0;
    int c1 = (i0 + 1 < n) ? cnt[i0 + 1] : 0;
    int ms = c0 + c1;
    ts[t] = ms;
    __syncthreads();
    for (int off = 1; off < 256; off <<= 1) {
        int u = (t >= off) ? ts[t - off] : 0;
        __syncthreads();
        ts[t] += u;
        __syncthreads();
    }
    int excl = ts[t] - ms + boff[blockIdx.x];
    if (i0 < n) cptr[i0] = excl;
    if (i0 + 1 < n) cptr[i0 + 1] = excl + c0;
    if (i0 == n - 1) cptr[n] = excl + c0;
    else if (i0 + 1 == n - 1) cptr[n] = excl + c0 + c1;
}

// ---------- CSR fill: slot fully determined, zero atomics ----------
__global__ void k_fill2(const int* __restrict__ src, const int* __restrict__ dst,
                        const unsigned int* __restrict__ epack,
                        const int* __restrict__ cptr, const u16* __restrict__ Bp,
                        int* __restrict__ adj, int E) {
    const int e0 = blockIdx.x * 1024 + threadIdx.x;
#pragma unroll
    for (int l = 0; l < 4; ++l) {
        int e = e0 + l * 256;
        if (e < E) {
            int d = dst[e];
            unsigned int pk = epack[e];
            int x = (int)(pk >> 16);
            int pos = (int)(pk & 0xFFFFu);
            adj[cptr[d] + (int)Bp[(size_t)d * 8 + x] + pos] = src[e];
        }
    }
}

// ---------- graph ranges: batch is sorted -> binary search lower bounds ----------
__global__ void k_gfind(const int* __restrict__ batch, int* __restrict__ gptr, int n) {
    int g = blockIdx.x * 64 + threadIdx.x;
    if (g > N_GRAPHSC) return;
    int lo = 0, hi = n;
    while (lo < hi) {
        int mid = (lo + hi) >> 1;
        if (batch[mid] < g) lo = mid + 1; else hi = mid;
    }
    gptr[g] = lo;
}

// ---------- aggregation v4: fp8 gather (16 B/lane), fp32 accumulate, bf16 out ----------
// F = features = row bytes (fp8). LPR lanes per row; RPI = 64/LPR rows per instruction.
template <int F>
__global__ __launch_bounds__(256) void k_aggregate4(
    const unsigned char* __restrict__ q8, const int* __restrict__ cptr,
    const int* __restrict__ adj, const float* __restrict__ di,
    u16* __restrict__ out, int n) {
    constexpr int LPR = F / 16;       // 8 (F=128) or 16 (F=256)
    constexpr int RPI = 64 / LPR;     // 8 or 4 rows per instruction
    const int lane = threadIdx.x & 63;
    const int node = blockIdx.x * 4 + (threadIdx.x >> 6);
    if (node >= n) return;
    const int sub = lane / LPR;       // row-slot
    const int li  = lane % LPR;       // 16B chunk within row
    const int p0 = cptr[node], p1 = cptr[node + 1];
    const float d = di[node];
    const unsigned char* base = q8 + (size_t)li * 16;
    float a[16];
#pragma unroll
    for (int e = 0; e < 16; ++e) a[e] = 0.f;

    int j = p0;
    while (j < p1) {
        int take = p1 - j; if (take > 64) take = 64;
        int myidx = (lane < take) ? adj[j + lane] : 0;
        const int ng = (take + RPI - 1) / RPI;
        for (int g0 = 0; g0 < ng; g0 += 4) {
            int sidx[4]; float m[4];
#pragma unroll
            for (int u = 0; u < 4; ++u) {
                int nb = (g0 + u) * RPI + sub;
                sidx[u] = __shfl(myidx, nb & 63);
                m[u] = (nb < take) ? 1.f : 0.f;
            }
            uint4 hv[4];
#pragma unroll
            for (int u = 0; u < 4; ++u)
                hv[u] = *(const uint4*)(base + (size_t)sidx[u] * F);
#pragma unroll
            for (int u = 0; u < 4; ++u) {
                float f[16];
                dq16(hv[u], f);
#pragma unroll
                for (int e = 0; e < 16; ++e) a[e] = fmaf(f[e], m[u], a[e]);
            }
        }
        j += take;
    }
    // combine row-slot partials
#pragma unroll
    for (int off = LPR; off < 64; off <<= 1)
#pragma unroll
        for (int e = 0; e < 16; ++e) a[e] += __shfl_xor(a[e], off);
    if (sub == 0) {
        uint4 o0 = make_uint4(pk2(a[0] * d, a[1] * d), pk2(a[2] * d, a[3] * d),
                              pk2(a[4] * d, a[5] * d), pk2(a[6] * d, a[7] * d));
        uint4 o1 = make_uint4(pk2(a[8] * d, a[9] * d), pk2(a[10] * d, a[11] * d),
                              pk2(a[12] * d, a[13] * d), pk2(a[14] * d, a[15] * d));
        *(uint4*)(out + (size_t)node * F + li * 16) = o0;
        *(uint4*)(out + (size_t)node * F + li * 16 + 8) = o1;
    }
}

// ---------- GEMM + fused column-stat partials ----------
__global__ __launch_bounds__(256) void k_gemm(
    const u16* __restrict__ A1, int K1,
    const u16* __restrict__ A2, int K2,
    const u16* __restrict__ Wt,
    u16* __restrict__ C, int M, float* __restrict__ statpart) {
    const int K = K1 + K2;
    __shared__ __align__(16) u16 Al[128 * 40];
    __shared__ __align__(16) u16 Bl[128 * 40];
    __shared__ float Ssum[2][128];
    __shared__ float Ssq[2][128];
    const int t = threadIdx.x;
    const int lane = t & 63;
    const int wave = t >> 6;
    const int wr = (wave >> 1) * 64, wc = (wave & 1) * 64;
    const int quad = lane >> 4, l15 = lane & 15;
    const int rowBase = blockIdx.x * 128;
    const int colBase = blockIdx.y * 128;

    floatx4 acc[4][4];
#pragma unroll
    for (int i = 0; i < 4; ++i)
#pragma unroll
        for (int j = 0; j < 4; ++j)
            acc[i][j] = (floatx4){0.f, 0.f, 0.f, 0.f};

    const int r0 = t >> 2;             // 0..63
    const int ch0 = (t & 3) * 8;       // 0,8,16,24 (elements)

    for (int kt = 0; kt < K; kt += 32) {
        const u16* As; int lda, kloc;
        if (kt < K1) { As = A1; lda = K1; kloc = kt; }
        else         { As = A2; lda = K2; kloc = kt - K1; }
#pragma unroll
        for (int l = 0; l < 2; ++l) {
            const int r = r0 + l * 64;
            const int grow = rowBase + r;
            uint4 va = make_uint4(0u, 0u, 0u, 0u);
            if (grow < M) va = *(const uint4*)(As + (size_t)grow * lda + (kloc + ch0));
            *(uint4*)(Al + r * 40 + ch0) = va;
            uint4 vb = *(const uint4*)(Wt + (size_t)(colBase + r) * K + (kt + ch0));
            *(uint4*)(Bl + r * 40 + ch0) = vb;
        }
        __syncthreads();
        short8 af[4], bfr[4];
#pragma unroll
        for (int i = 0; i < 4; ++i) af[i] = *(const short8*)(Al + (wr + i * 16 + l15) * 40 + quad * 8);
#pragma unroll
        for (int j = 0; j < 4; ++j) bfr[j] = *(const short8*)(Bl + (wc + j * 16 + l15) * 40 + quad * 8);
#pragma unroll
        for (int i = 0; i < 4; ++i)
#pragma unroll
            for (int j = 0; j < 4; ++j)
                acc[i][j] = __builtin_amdgcn_mfma_f32_16x16x32_bf16(af[i], bfr[j], acc[i][j], 0, 0, 0);
        __syncthreads();
    }
    // fused column stats (pad rows have zero A -> zero acc, contribute nothing)
    if (statpart) {
#pragma unroll
        for (int j = 0; j < 4; ++j) {
            float s = 0.f, q = 0.f;
#pragma unroll
            for (int i = 0; i < 4; ++i)
#pragma unroll
                for (int r = 0; r < 4; ++r) {
                    float v = acc[i][j][r];
                    s += v; q += v * v;
                }
            s += __shfl_down(s, 32); s += __shfl_down(s, 16);
            q += __shfl_down(q, 32); q += __shfl_down(q, 16);
            if (lane < 16) {
                Ssum[wr >> 6][wc + j * 16 + l15] = s;
                Ssq[wr >> 6][wc + j * 16 + l15] = q;
            }
        }
        __syncthreads();
        if (t < 128) {
            const size_t bid = (size_t)blockIdx.y * GEMM_BX + blockIdx.x;
            statpart[bid * 256 + t] = Ssum[0][t] + Ssum[1][t];
            statpart[bid * 256 + 128 + t] = Ssq[0][t] + Ssq[1][t];
        }
    }
#pragma unroll
    for (int i = 0; i < 4; ++i) {
#pragma unroll
        for (int r = 0; r < 4; ++r) {
            const int row = rowBase + wr + i * 16 + quad * 4 + r;
            if (row < M) {
#pragma unroll
                for (int j = 0; j < 4; ++j) {
                    const int col = colBase + wc + j * 16 + l15;
                    C[(size_t)row * HDIM + col] = f2bf(acc[i][j][r]);
                }
            }
        }
    }
}

// ---------- fused stat reduce + BN scale/shift: one block per column ----------
__global__ void k_statbn(const float* __restrict__ sp, const float* __restrict__ g,
                         const float* __restrict__ beta, float* __restrict__ sc,
                         float* __restrict__ sh, float invN) {
    const int c = blockIdx.x;                        // 0..255
    const size_t base = (size_t)(c >> 7) * GEMM_BX;  // which column-tile
    const int off = c & 127;
    float s = 0.f, q = 0.f;
    for (int bx = threadIdx.x; bx < GEMM_BX; bx += 64) {
        s += sp[(base + bx) * 256 + off];
        q += sp[(base + bx) * 256 + 128 + off];
    }
#pragma unroll
    for (int o = 32; o > 0; o >>= 1) { s += __shfl_down(s, o); q += __shfl_down(q, o); }
    if (threadIdx.x == 0) {
        float mu = s * invN;
        float var = q * invN - mu * mu;
        float k = g[c] * rsqrtf(var + 1e-5f);
        sc[c] = k;
        sh[c] = beta[c] - mu * k;
    }
}

// ---------- h_next = relu(C*scale+shift) + identity (+res_b); fp8 copy; optional dot ----------
__global__ __launch_bounds__(256) void k_finalize2(
    const u16* __restrict__ Cb, const u16* __restrict__ iden,
    const float* __restrict__ sc, const float* __restrict__ sh,
    const float* __restrict__ resb, const float* __restrict__ w,
    u16* __restrict__ hout, unsigned char* __restrict__ q8out,
    float* __restrict__ nodedot) {
    const int i = blockIdx.x * 256 + threadIdx.x;   // tile id, 32 elems each; grid exact
    const size_t base = (size_t)i * 32;
    const int c0 = (i & 7) * 32;                    // column base within row
    const uint4* cp = (const uint4*)(Cb + base);
    const uint4* ip = (const uint4*)(iden + base);
    uint4 cv[4], iv[4];
#pragma unroll
    for (int q = 0; q < 4; ++q) cv[q] = cp[q];
#pragma unroll
    for (int q = 0; q < 4; ++q) iv[q] = ip[q];

    float dot = 0.f;
    unsigned int qa[8];
    uint4* op = (uint4*)(hout + base);
#pragma unroll
    for (int q = 0; q < 4; ++q) {
        float cf[8], df[8];
        up8(cv[q], cf); up8(iv[q], df);
        const float4 s0 = ((const float4*)(sc + c0 + q * 8))[0];
        const float4 s1 = ((const float4*)(sc + c0 + q * 8))[1];
        const float4 h0 = ((const float4*)(sh + c0 + q * 8))[0];
        const float4 h1 = ((const float4*)(sh + c0 + q * 8))[1];
        float scf[8] = {s0.x, s0.y, s0.z, s0.w, s1.x, s1.y, s1.z, s1.w};
        float shf[8] = {h0.x, h0.y, h0.z, h0.w, h1.x, h1.y, h1.z, h1.w};
        float rbf[8] = {0.f, 0.f, 0.f, 0.f, 0.f, 0.f, 0.f, 0.f};
        if (resb) {
            const float4 r0 = ((const float4*)(resb + c0 + q * 8))[0];
            const float4 r1 = ((const float4*)(resb + c0 + q * 8))[1];
            rbf[0] = r0.x; rbf[1] = r0.y; rbf[2] = r0.z; rbf[3] = r0.w;
            rbf[4] = r1.x; rbf[5] = r1.y; rbf[6] = r1.z; rbf[7] = r1.w;
        }
        float o[8];
#pragma unroll
        for (int e = 0; e < 8; ++e) {
            float v = cf[e] * scf[e] + shf[e];
            o[e] = fmaxf(v, 0.f) + df[e] + rbf[e];
        }
        if (q8out) {
            unsigned int wlo = __builtin_amdgcn_cvt_pk_fp8_f32(o[0], o[1], 0, false);
            wlo = __builtin_amdgcn_cvt_pk_fp8_f32(o[2], o[3], wlo, true);
            unsigned int whi = __builtin_amdgcn_cvt_pk_fp8_f32(o[4], o[5], 0, false);
            whi = __builtin_amdgcn_cvt_pk_fp8_f32(o[6], o[7], whi, true);
            qa[q * 2] = wlo; qa[q * 2 + 1] = whi;
        }
        if (nodedot) {
            const float4 w0 = ((const float4*)(w + c0 + q * 8))[0];
            const float4 w1 = ((const float4*)(w + c0 + q * 8))[1];
            dot += o[0] * w0.x + o[1] * w0.y + o[2] * w0.z + o[3] * w0.w
                 + o[4] * w1.x + o[5] * w1.y + o[6] * w1.z + o[7] * w1.w;
        }
        op[q] = make_uint4(pk2(o[0], o[1]), pk2(o[2], o[3]), pk2(o[4], o[5]), pk2(o[6], o[7]));
    }
    if (q8out) {
        *(uint4*)(q8out + base) = make_uint4(qa[0], qa[1], qa[2], qa[3]);
        *(uint4*)(q8out + base + 16) = make_uint4(qa[4], qa[5], qa[6], qa[7]);
    }
    if (nodedot) {
        dot += __shfl_down(dot, 4);
        dot += __shfl_down(dot, 2);
        dot += __shfl_down(dot, 1);
        if ((threadIdx.x & 7) == 0) nodedot[i >> 3] = dot;
    }
}

// ---------- readout stage 2: one block per graph, contiguous segment sum ----------
__global__ void k_pool(const float* __restrict__ nodedot, const int* __restrict__ gptr,
                       const float* __restrict__ lb, float* __restrict__ out) {
    const int g = blockIdx.x;
    const int r0 = gptr[g], r1 = gptr[g + 1];
    float s = 0.f;
    for (int i = r0 + threadIdx.x; i < r1; i += 256) s += nodedot[i];
#pragma unroll
    for (int off = 32; off > 0; off >>= 1) s += __shfl_down(s, off);
    __shared__ float red[4];
    const int wave = threadIdx.x >> 6;
    if ((threadIdx.x & 63) == 0) red[wave] = s;
    __syncthreads();
    if (threadIdx.x == 0) {
        float tot = red[0] + red[1] + red[2] + red[3];
        int c = r1 - r0; if (c < 1) c = 1;
        out[g] = tot / (float)c + lb[0];
    }
}

extern "C" void kernel_launch(void* const* d_in, const int* in_sizes, int n_in,
                              void* d_out, int out_size, void* d_ws, size_t ws_size,
                              hipStream_t stream) {
    const float* x     = (const float*)d_in[0];
    const int*   ei    = (const int*)d_in[1];
    const int*   batch = (const int*)d_in[2];
    const float* Wl1 = (const float*)d_in[3];
    const float* Wr1 = (const float*)d_in[5];
    const float* g1  = (const float*)d_in[6];
    const float* be1 = (const float*)d_in[7];
    const float* Wl2 = (const float*)d_in[8];
    const float* Wr2 = (const float*)d_in[10];
    const float* g2  = (const float*)d_in[11];
    const float* be2 = (const float*)d_in[12];
    const float* Wl3 = (const float*)d_in[13];
    const float* Wr3 = (const float*)d_in[15];
    const float* g3  = (const float*)d_in[16];
    const float* be3 = (const float*)d_in[17];
    const float* Wl4 = (const float*)d_in[18];
    const float* Wr4 = (const float*)d_in[20];
    const float* g4  = (const float*)d_in[21];
    const float* be4 = (const float*)d_in[22];
    const float* resW = (const float*)d_in[23];
    const float* resb = (const float*)d_in[24];
    const float* linW = (const float*)d_in[25];
    const float* linb = (const float*)d_in[26];
    float* out = (float*)d_out;

    char* p = (char*)d_ws;
    auto carve = [&](size_t bytes) -> char* {
        char* r = p;
        p += (bytes + 255) & ~(size_t)255;
        return r;
    };
    int*   cptr    = (int*)carve((size_t)(N_NODESC + 1) * 4);
    int*   counts  = (int*)carve((size_t)N_NODESC * 4);
    float* dinv    = (float*)carve((size_t)N_NODESC * 4);
    int*   gptr    = (int*)carve((N_GRAPHSC + 1) * 4);
    float* nodedot = (float*)carve((size_t)N_NODESC * 4);
    float* statpart= (float*)carve((size_t)GEMM_NBLK * 256 * 4);
    float* scale   = (float*)carve(256 * 4);
    float* shift   = (float*)carve(256 * 4);
    int*   bsum    = (int*)carve(SCAN_NB * 4);
    int*   boff    = (int*)carve(SCAN_NB * 4);
    int*   adj     = (int*)carve((size_t)N_EDGESC * 4);
    u16*   Wt1     = (u16*)carve(256 * 256 * 2);
    u16*   Wt2     = (u16*)carve(256 * 512 * 2);
    u16*   Wt3     = (u16*)carve(256 * 512 * 2);
    u16*   Wt4     = (u16*)carve(256 * 512 * 2);
    u16*   Rt      = (u16*)carve(256 * 128 * 2);
    u16*   xb      = (u16*)carve((size_t)N_NODESC * F_INC * 2);
    u16*   hA      = (u16*)carve((size_t)N_NODESC * HDIM * 2);
    u16*   hB      = (u16*)carve((size_t)N_NODESC * HDIM * 2);
    u16*   agg     = (u16*)carve((size_t)N_NODESC * HDIM * 2);  // aliased as res for layer 1
    u16*   Cb      = (u16*)carve((size_t)N_NODESC * HDIM * 2);
    unsigned char* q8 = (unsigned char*)carve((size_t)N_NODESC * HDIM); // fp8 gather buffer (single: only one live h at a time)

    // CSR-build temporaries alias big buffers that are dead during the build:
    unsigned int* P     = (unsigned int*)hA;  // 3.2 MB; dead before hA written (layer-1 finalize)
    unsigned int* epack = (unsigned int*)Cb;  // 6.4 MB; dead before Cb written (layer-1 gemm)
    u16*          Bp    = (u16*)hB;           // 1.6 MB; dead before hB written (layer-2 finalize)
    unsigned char* xb8  = q8;                 // x fp8 (12.8 MB); dead before finalize(1) overwrites q8

    hipMemsetAsync(P, 0, (size_t)8 * N_NODESC * 4, stream);

    const int* srcp = ei;
    const int* dstp = ei + N_EDGESC;

    // weight prep + x conversion (bf16 + fp8)
    k_wcat<<<(256 * 256 + 255) / 256, 256, 0, stream>>>(Wl1, Wr1, 128, 128, Wt1);
    k_wcat<<<(256 * 512 + 255) / 256, 256, 0, stream>>>(Wl2, Wr2, 256, 256, Wt2);
    k_wcat<<<(256 * 512 + 255) / 256, 256, 0, stream>>>(Wl3, Wr3, 256, 256, Wt3);
    k_wcat<<<(256 * 512 + 255) / 256, 256, 0, stream>>>(Wl4, Wr4, 256, 256, Wt4);
    k_wcat<<<(256 * 128 + 255) / 256, 256, 0, stream>>>(resW, resW, 128, 0, Rt);
    k_f2both<<<(N_NODESC * F_INC / 8 + 255) / 256, 256, 0, stream>>>(x, xb, xb8, N_NODESC * F_INC / 8);

    // graph structure (no device-scope atomics anywhere)
    k_gfind<<<5, 64, 0, stream>>>(batch, gptr, N_NODESC);
    k_countP<<<(N_EDGESC + 1023) / 1024, 256, 0, stream>>>(dstp, P, epack, N_EDGESC);
    k_reduceP<<<(N_NODESC + 255) / 256, 256, 0, stream>>>(P, counts, dinv, Bp, N_NODESC);
    k_scan_bsum<<<SCAN_NB, 256, 0, stream>>>(counts, bsum, N_NODESC);
    k_scan_boff<<<1, 256, 0, stream>>>(bsum, boff, SCAN_NB);
    k_scan_write<<<SCAN_NB, 256, 0, stream>>>(counts, boff, cptr, N_NODESC);
    k_fill2<<<(N_EDGESC + 1023) / 1024, 256, 0, stream>>>(srcp, dstp, epack, cptr, Bp, adj, N_EDGESC);

    dim3 gGemm(GEMM_BX, 2);
    const float invN = 1.0f / (float)N_NODESC;
    const int finBlocks = N_NODESC * HDIM / 32 / 256;  // 3125, exact

    // ---- layer 1 ----
    k_aggregate4<128><<<25000, 256, 0, stream>>>(xb8, cptr, adj, dinv, agg, N_NODESC);
    k_gemm<<<gGemm, 256, 0, stream>>>(agg, 128, xb, 128, Wt1, Cb, N_NODESC, statpart);
    k_gemm<<<gGemm, 256, 0, stream>>>(xb, 128, xb, 0, Rt, agg, N_NODESC, nullptr);  // res reuses agg
    k_statbn<<<256, 64, 0, stream>>>(statpart, g1, be1, scale, shift, invN);
    k_finalize2<<<finBlocks, 256, 0, stream>>>(Cb, agg, scale, shift, resb, nullptr, hA, q8, nullptr);

    // ---- layer 2 ----
    k_aggregate4<256><<<25000, 256, 0, stream>>>(q8, cptr, adj, dinv, agg, N_NODESC);
    k_gemm<<<gGemm, 256, 0, stream>>>(agg, 256, hA, 256, Wt2, Cb, N_NODESC, statpart);
    k_statbn<<<256, 64, 0, stream>>>(statpart, g2, be2, scale, shift, invN);
    k_finalize2<<<finBlocks, 256, 0, stream>>>(Cb, hA, scale, shift, nullptr, nullptr, hB, q8, nullptr);

    // ---- layer 3 ----
    k_aggregate4<256><<<25000, 256, 0, stream>>>(q8, cptr, adj, dinv, agg, N_NODESC);
    k_gemm<<<gGemm, 256, 0, stream>>>(agg, 256, hB, 256, Wt3, Cb, N_NODESC, statpart);
    k_statbn<<<256, 64, 0, stream>>>(statpart, g3, be3, scale, shift, invN);
    k_finalize2<<<finBlocks, 256, 0, stream>>>(Cb, hB, scale, shift, nullptr, nullptr, hA, q8, nullptr);

    // ---- layer 4 (fused per-node dot with lin_W; no fp8 needed) ----
    k_aggregate4<256><<<25000, 256, 0, stream>>>(q8, cptr, adj, dinv, agg, N_NODESC);
    k_gemm<<<gGemm, 256, 0, stream>>>(agg, 256, hA, 256, Wt4, Cb, N_NODESC, statpart);
    k_statbn<<<256, 64, 0, stream>>>(statpart, g4, be4, scale, shift, invN);
    k_finalize2<<<finBlocks, 256, 0, stream>>>(Cb, hA, scale, shift, nullptr, linW, hB, nullptr, nodedot);

    // ---- pooled mean + lin_b ----
    k_pool<<<N_GRAPHSC, 256, 0, stream>>>(nodedot, gptr, linb, out);
}

// Round 8
// 946.346 us; speedup vs baseline: 1.2287x; 1.0745x over previous
//
#include <hip/hip_runtime.h>

typedef unsigned short u16;
typedef __attribute__((ext_vector_type(8))) short short8;
typedef __attribute__((ext_vector_type(4))) float floatx4;
typedef __attribute__((ext_vector_type(2))) float floatx2;

#define N_NODESC 100000
#define N_EDGESC 1600000
#define N_GRAPHSC 256
#define F_INC 128
#define HDIM 256
#define SCAN_CHUNK 512
#define SCAN_NB ((N_NODESC + SCAN_CHUNK - 1) / SCAN_CHUNK)  // 196
#define GEMM_BX 782
#define GEMM_NBLK (GEMM_BX * 2)

// async global->LDS DMA, 16B per lane, dest = wave-uniform base + lane*16
#define GLDS16(g, l) __builtin_amdgcn_global_load_lds( \
    (const __attribute__((address_space(1))) unsigned int*)(g), \
    (__attribute__((address_space(3))) unsigned int*)(l), 16, 0, 0)

__device__ __forceinline__ float bf2f(u16 u) {
    union { unsigned int i; float f; } v; v.i = ((unsigned int)u) << 16; return v.f;
}
__device__ __forceinline__ u16 f2bf(float f) {
    union { float f; unsigned int i; } v; v.f = f;
    unsigned int b = v.i;
    b += 0x7fffu + ((b >> 16) & 1u);
    return (u16)(b >> 16);
}
__device__ __forceinline__ void up8(uint4 v, float* f) {
    f[0] = bf2f((u16)(v.x & 0xffff)); f[1] = bf2f((u16)(v.x >> 16));
    f[2] = bf2f((u16)(v.y & 0xffff)); f[3] = bf2f((u16)(v.y >> 16));
    f[4] = bf2f((u16)(v.z & 0xffff)); f[5] = bf2f((u16)(v.z >> 16));
    f[6] = bf2f((u16)(v.w & 0xffff)); f[7] = bf2f((u16)(v.w >> 16));
}
__device__ __forceinline__ unsigned int pk2(float a, float b) {
    return (unsigned int)f2bf(a) | ((unsigned int)f2bf(b) << 16);
}
// decode 16 fp8(e4m3) from uint4 -> 16 floats (HW v_cvt_pk_f32_fp8, OCP on gfx950)
__device__ __forceinline__ void dq16(uint4 v, float* f) {
    floatx2 p;
    p = __builtin_amdgcn_cvt_pk_f32_fp8(v.x, false); f[0] = p[0]; f[1] = p[1];
    p = __builtin_amdgcn_cvt_pk_f32_fp8(v.x, true);  f[2] = p[0]; f[3] = p[1];
    p = __builtin_amdgcn_cvt_pk_f32_fp8(v.y, false); f[4] = p[0]; f[5] = p[1];
    p = __builtin_amdgcn_cvt_pk_f32_fp8(v.y, true);  f[6] = p[0]; f[7] = p[1];
    p = __builtin_amdgcn_cvt_pk_f32_fp8(v.z, false); f[8] = p[0]; f[9] = p[1];
    p = __builtin_amdgcn_cvt_pk_f32_fp8(v.z, true);  f[10] = p[0]; f[11] = p[1];
    p = __builtin_amdgcn_cvt_pk_f32_fp8(v.w, false); f[12] = p[0]; f[13] = p[1];
    p = __builtin_amdgcn_cvt_pk_f32_fp8(v.w, true);  f[14] = p[0]; f[15] = p[1];
}
// XCC_ID hwreg (id=20) — measured working on gfx950 (learn_hip m09)
__device__ __forceinline__ int get_xcd() {
    int x;
    asm volatile("s_getreg_b32 %0, hwreg(20, 0, 4)" : "=s"(x));
    return x & 7;
}

// ---------- weight prep: out[c*K + k] = (k<K1 ? Wl[k][c] : Wr[k-K1][c]) as bf16 ----------
__global__ void k_wcat(const float* __restrict__ Wl, const float* __restrict__ Wr,
                       int K1, int K2, u16* __restrict__ out) {
    int K = K1 + K2;
    int idx = blockIdx.x * 256 + threadIdx.x;
    if (idx >= 256 * K) return;
    int c = idx / K, k = idx - c * K;
    float v = (k < K1) ? Wl[k * 256 + c] : Wr[(k - K1) * 256 + c];
    out[idx] = f2bf(v);
}

// ---------- fp32 -> bf16 + fp8 dual convert (8 elems/thread) ----------
__global__ void k_f2both(const float* __restrict__ in, u16* __restrict__ outb,
                         unsigned char* __restrict__ out8, int n8) {
    int i = blockIdx.x * 256 + threadIdx.x;
    if (i >= n8) return;
    float4 v0 = ((const float4*)in)[2 * i];
    float4 v1 = ((const float4*)in)[2 * i + 1];
    ((uint4*)outb)[i] = make_uint4(pk2(v0.x, v0.y), pk2(v0.z, v0.w),
                                   pk2(v1.x, v1.y), pk2(v1.z, v1.w));
    unsigned int wlo = __builtin_amdgcn_cvt_pk_fp8_f32(v0.x, v0.y, 0, false);
    wlo = __builtin_amdgcn_cvt_pk_fp8_f32(v0.z, v0.w, wlo, true);
    unsigned int whi = __builtin_amdgcn_cvt_pk_fp8_f32(v1.x, v1.y, 0, false);
    whi = __builtin_amdgcn_cvt_pk_fp8_f32(v1.z, v1.w, whi, true);
    ((uint2*)out8)[i] = make_uint2(wlo, whi);
}

// ---------- edge count: per-XCD partial histograms, XCD-local (workgroup-scope) atomics ----------
__global__ void k_countP(const int* __restrict__ dst, unsigned int* __restrict__ P,
                         unsigned int* __restrict__ epack, int E) {
    const int xcd = get_xcd();
    unsigned int* Px = P + (size_t)xcd * N_NODESC;
    const int e0 = blockIdx.x * 1024 + threadIdx.x;
#pragma unroll
    for (int l = 0; l < 4; ++l) {
        int e = e0 + l * 256;
        if (e < E) {
            int d = dst[e];
            unsigned int pos = __hip_atomic_fetch_add(&Px[d], 1u, __ATOMIC_RELAXED,
                                                      __HIP_MEMORY_SCOPE_WORKGROUP);
            epack[e] = ((unsigned int)xcd << 16) | pos;
        }
    }
}

// ---------- reduce partials: counts, 1/deg, per-(node,xcd) base offsets ----------
__global__ void k_reduceP(const unsigned int* __restrict__ P, int* __restrict__ counts,
                          float* __restrict__ dinv, u16* __restrict__ Bp, int n) {
    int d = blockIdx.x * 256 + threadIdx.x;
    if (d >= n) return;
    unsigned int s = 0;
    u16 b[8];
#pragma unroll
    for (int x = 0; x < 8; ++x) {
        b[x] = (u16)s;
        s += P[(size_t)x * n + d];
    }
    counts[d] = (int)s;
    dinv[d] = 1.0f / (float)(s > 1u ? s : 1u);
    ushort4* bp = (ushort4*)(Bp + (size_t)d * 8);
    bp[0] = make_ushort4(b[0], b[1], b[2], b[3]);
    bp[1] = make_ushort4(b[4], b[5], b[6], b[7]);
}

// ---------- 3-phase scan over counts -> csr_ptr ----------
__global__ void k_scan_bsum(const int* __restrict__ cnt, int* __restrict__ bsum, int n) {
    __shared__ int ts[256];
    int t = threadIdx.x;
    int i0 = blockIdx.x * SCAN_CHUNK + t * 2;
    int c0 = (i0 < n) ? cnt[i0] : 0;
    int c1 = (i0 + 1 < n) ? cnt[i0 + 1] : 0;
    ts[t] = c0 + c1;
    __syncthreads();
    for (int off = 128; off > 0; off >>= 1) {
        if (t < off) ts[t] += ts[t + off];
        __syncthreads();
    }
    if (t == 0) bsum[blockIdx.x] = ts[0];
}

__global__ void k_scan_boff(const int* __restrict__ bsum, int* __restrict__ boff, int nb) {
    __shared__ int ts[256];
    int t = threadIdx.x;
    int v = (t < nb) ? bsum[t] : 0;
    ts[t] = v;
    __syncthreads();
    for (int off = 1; off < 256; off <<= 1) {
        int u = (t >= off) ? ts[t - off] : 0;
        __syncthreads();
        ts[t] += u;
        __syncthreads();
    }
    if (t < nb) boff[t] = ts[t] - v;  // exclusive
}

__global__ void k_scan_write(const int* __restrict__ cnt, const int* __restrict__ boff,
                             int* __restrict__ cptr, int n) {
    __shared__ int ts[256];
    int t = threadIdx.x;
    int i0 = blockIdx.x * SCAN_CHUNK + t * 2;
    int c0 = (i0 < n) ? cnt[i0] : 0;
    int c1 = (i0 + 1 < n) ? cnt[i0 + 1] : 0;
    int ms = c0 + c1;
    ts[t] = ms;
    __syncthreads();
    for (int off = 1; off < 256; off <<= 1) {
        int u = (t >= off) ? ts[t - off] : 0;
        __syncthreads();
        ts[t] += u;
        __syncthreads();
    }
    int excl = ts[t] - ms + boff[blockIdx.x];
    if (i0 < n) cptr[i0] = excl;
    if (i0 + 1 < n) cptr[i0 + 1] = excl + c0;
    if (i0 == n - 1) cptr[n] = excl + c0;
    else if (i0 + 1 == n - 1) cptr[n] = excl + c0 + c1;
}

// ---------- CSR fill: slot fully determined, zero atomics ----------
__global__ void k_fill2(const int* __restrict__ src, const int* __restrict__ dst,
                        const unsigned int* __restrict__ epack,
                        const int* __restrict__ cptr, const u16* __restrict__ Bp,
                        int* __restrict__ adj, int E) {
    const int e0 = blockIdx.x * 1024 + threadIdx.x;
#pragma unroll
    for (int l = 0; l < 4; ++l) {
        int e = e0 + l * 256;
        if (e < E) {
            int d = dst[e];
            unsigned int pk = epack[e];
            int x = (int)(pk >> 16);
            int pos = (int)(pk & 0xFFFFu);
            adj[cptr[d] + (int)Bp[(size_t)d * 8 + x] + pos] = src[e];
        }
    }
}

// ---------- graph ranges: batch is sorted -> binary search lower bounds ----------
__global__ void k_gfind(const int* __restrict__ batch, int* __restrict__ gptr, int n) {
    int g = blockIdx.x * 64 + threadIdx.x;
    if (g > N_GRAPHSC) return;
    int lo = 0, hi = n;
    while (lo < hi) {
        int mid = (lo + hi) >> 1;
        if (batch[mid] < g) lo = mid + 1; else hi = mid;
    }
    gptr[g] = lo;
}

// ---------- aggregation v4: fp8 gather (16 B/lane), fp32 accumulate, bf16 out ----------
template <int F>
__global__ __launch_bounds__(256) void k_aggregate4(
    const unsigned char* __restrict__ q8, const int* __restrict__ cptr,
    const int* __restrict__ adj, const float* __restrict__ di,
    u16* __restrict__ out, int n) {
    constexpr int LPR = F / 16;       // 8 (F=128) or 16 (F=256)
    constexpr int RPI = 64 / LPR;     // 8 or 4 rows per instruction
    const int lane = threadIdx.x & 63;
    const int node = blockIdx.x * 4 + (threadIdx.x >> 6);
    if (node >= n) return;
    const int sub = lane / LPR;       // row-slot
    const int li  = lane % LPR;       // 16B chunk within row
    const int p0 = cptr[node], p1 = cptr[node + 1];
    const float d = di[node];
    const unsigned char* base = q8 + (size_t)li * 16;
    float a[16];
#pragma unroll
    for (int e = 0; e < 16; ++e) a[e] = 0.f;

    int j = p0;
    while (j < p1) {
        int take = p1 - j; if (take > 64) take = 64;
        int myidx = (lane < take) ? adj[j + lane] : 0;
        const int ng = (take + RPI - 1) / RPI;
        for (int g0 = 0; g0 < ng; g0 += 4) {
            int sidx[4]; float m[4];
#pragma unroll
            for (int u = 0; u < 4; ++u) {
                int nb = (g0 + u) * RPI + sub;
                sidx[u] = __shfl(myidx, nb & 63);
                m[u] = (nb < take) ? 1.f : 0.f;
            }
            uint4 hv[4];
#pragma unroll
            for (int u = 0; u < 4; ++u)
                hv[u] = *(const uint4*)(base + (size_t)sidx[u] * F);
#pragma unroll
            for (int u = 0; u < 4; ++u) {
                float f[16];
                dq16(hv[u], f);
#pragma unroll
                for (int e = 0; e < 16; ++e) a[e] = fmaf(f[e], m[u], a[e]);
            }
        }
        j += take;
    }
    // combine row-slot partials
#pragma unroll
    for (int off = LPR; off < 64; off <<= 1)
#pragma unroll
        for (int e = 0; e < 16; ++e) a[e] += __shfl_xor(a[e], off);
    if (sub == 0) {
        uint4 o0 = make_uint4(pk2(a[0] * d, a[1] * d), pk2(a[2] * d, a[3] * d),
                              pk2(a[4] * d, a[5] * d), pk2(a[6] * d, a[7] * d));
        uint4 o1 = make_uint4(pk2(a[8] * d, a[9] * d), pk2(a[10] * d, a[11] * d),
                              pk2(a[12] * d, a[13] * d), pk2(a[14] * d, a[15] * d));
        *(uint4*)(out + (size_t)node * F + li * 16) = o0;
        *(uint4*)(out + (size_t)node * F + li * 16 + 8) = o1;
    }
}

// ---------- GEMM v2: BK=64, async global_load_lds staging, XOR-swizzled tight LDS ----------
// LDS tile [128][64] u16, chunk (16B = 8 elems) stored at chunk_index ^ (row & 7).
__global__ __launch_bounds__(256, 4) void k_gemm(
    const u16* __restrict__ A1, int K1,
    const u16* __restrict__ A2, int K2,
    const u16* __restrict__ Wt,
    u16* __restrict__ C, int M, float* __restrict__ statpart) {
    const int K = K1 + K2;
    __shared__ __align__(16) u16 Al[128 * 64];
    __shared__ __align__(16) u16 Bl[128 * 64];
    __shared__ float Ssum[2][128];
    __shared__ float Ssq[2][128];
    const int t = threadIdx.x;
    const int lane = t & 63;
    const int wave = t >> 6;
    const int wr = (wave >> 1) * 64, wc = (wave & 1) * 64;
    const int quad = lane >> 4, l15 = lane & 15;
    const int rowBase = blockIdx.x * 128;
    const int colBase = blockIdx.y * 128;
    const bool fastA = (rowBase + 128 <= M);

    floatx4 acc[4][4];
#pragma unroll
    for (int i = 0; i < 4; ++i)
#pragma unroll
        for (int j = 0; j < 4; ++j)
            acc[i][j] = (floatx4){0.f, 0.f, 0.f, 0.f};

    const int rw = wave * 32 + (lane >> 3);  // staging row base (+8 per sub-instr)
    const int lch = lane & 7;                // this lane's LDS chunk slot

    for (int kt = 0; kt < K; kt += 64) {
        const u16* As; int lda, kloc;
        if (kt < K1) { As = A1; lda = K1; kloc = kt; }
        else         { As = A2; lda = K2; kloc = kt - K1; }
        // ---- B stage (always in-bounds): 4 DMA instrs per wave ----
#pragma unroll
        for (int ii = 0; ii < 4; ++ii) {
            const int row = rw + ii * 8;
            const int gc = lch ^ (row & 7);
            GLDS16(Wt + (size_t)(colBase + row) * K + (kt + gc * 8),
                   Bl + (size_t)(wave * 32 + ii * 8) * 64);
        }
        // ---- A stage ----
        if (fastA) {
#pragma unroll
            for (int ii = 0; ii < 4; ++ii) {
                const int row = rw + ii * 8;
                const int gc = lch ^ (row & 7);
                GLDS16(As + (size_t)(rowBase + row) * lda + (kloc + gc * 8),
                       Al + (size_t)(wave * 32 + ii * 8) * 64);
            }
        } else {
#pragma unroll
            for (int ii = 0; ii < 4; ++ii) {
                const int row = rw + ii * 8;
                const int gc = lch ^ (row & 7);
                const int grow = rowBase + row;
                uint4 v = make_uint4(0u, 0u, 0u, 0u);
                if (grow < M) v = *(const uint4*)(As + (size_t)grow * lda + (kloc + gc * 8));
                *(uint4*)(Al + (size_t)row * 64 + lch * 8) = v;
            }
        }
        __syncthreads();
#pragma unroll
        for (int kk = 0; kk < 2; ++kk) {
            const int gcq = kk * 4 + quad;  // global k-chunk this quad consumes
            short8 af[4], bfr[4];
#pragma unroll
            for (int i = 0; i < 4; ++i) {
                const int row = wr + i * 16 + l15;
                af[i] = *(const short8*)(Al + (size_t)row * 64 + ((gcq ^ (row & 7)) * 8));
            }
#pragma unroll
            for (int j = 0; j < 4; ++j) {
                const int row = wc + j * 16 + l15;
                bfr[j] = *(const short8*)(Bl + (size_t)row * 64 + ((gcq ^ (row & 7)) * 8));
            }
#pragma unroll
            for (int i = 0; i < 4; ++i)
#pragma unroll
                for (int j = 0; j < 4; ++j)
                    acc[i][j] = __builtin_amdgcn_mfma_f32_16x16x32_bf16(af[i], bfr[j], acc[i][j], 0, 0, 0);
        }
        __syncthreads();
    }
    // fused column stats (pad rows have zero A -> zero acc, contribute nothing)
    if (statpart) {
#pragma unroll
        for (int j = 0; j < 4; ++j) {
            float s = 0.f, q = 0.f;
#pragma unroll
            for (int i = 0; i < 4; ++i)
#pragma unroll
                for (int r = 0; r < 4; ++r) {
                    float v = acc[i][j][r];
                    s += v; q += v * v;
                }
            s += __shfl_down(s, 32); s += __shfl_down(s, 16);
            q += __shfl_down(q, 32); q += __shfl_down(q, 16);
            if (lane < 16) {
                Ssum[wr >> 6][wc + j * 16 + l15] = s;
                Ssq[wr >> 6][wc + j * 16 + l15] = q;
            }
        }
        __syncthreads();
        if (t < 128) {
            const size_t bid = (size_t)blockIdx.y * GEMM_BX + blockIdx.x;
            statpart[bid * 256 + t] = Ssum[0][t] + Ssum[1][t];
            statpart[bid * 256 + 128 + t] = Ssq[0][t] + Ssq[1][t];
        }
    }
#pragma unroll
    for (int i = 0; i < 4; ++i) {
#pragma unroll
        for (int r = 0; r < 4; ++r) {
            const int row = rowBase + wr + i * 16 + quad * 4 + r;
            if (row < M) {
#pragma unroll
                for (int j = 0; j < 4; ++j) {
                    const int col = colBase + wc + j * 16 + l15;
                    C[(size_t)row * HDIM + col] = f2bf(acc[i][j][r]);
                }
            }
        }
    }
}

// ---------- fused stat reduce + BN scale/shift: one block per column ----------
__global__ void k_statbn(const float* __restrict__ sp, const float* __restrict__ g,
                         const float* __restrict__ beta, float* __restrict__ sc,
                         float* __restrict__ sh, float invN) {
    const int c = blockIdx.x;                        // 0..255
    const size_t base = (size_t)(c >> 7) * GEMM_BX;  // which column-tile
    const int off = c & 127;
    float s = 0.f, q = 0.f;
    for (int bx = threadIdx.x; bx < GEMM_BX; bx += 64) {
        s += sp[(base + bx) * 256 + off];
        q += sp[(base + bx) * 256 + 128 + off];
    }
#pragma unroll
    for (int o = 32; o > 0; o >>= 1) { s += __shfl_down(s, o); q += __shfl_down(q, o); }
    if (threadIdx.x == 0) {
        float mu = s * invN;
        float var = q * invN - mu * mu;
        float k = g[c] * rsqrtf(var + 1e-5f);
        sc[c] = k;
        sh[c] = beta[c] - mu * k;
    }
}

// ---------- h_next = relu(C*scale+shift) + identity (+res_b); fp8 copy; optional dot ----------
__global__ __launch_bounds__(256) void k_finalize2(
    const u16* __restrict__ Cb, const u16* __restrict__ iden,
    const float* __restrict__ sc, const float* __restrict__ sh,
    const float* __restrict__ resb, const float* __restrict__ w,
    u16* __restrict__ hout, unsigned char* __restrict__ q8out,
    float* __restrict__ nodedot) {
    const int i = blockIdx.x * 256 + threadIdx.x;   // tile id, 32 elems each; grid exact
    const size_t base = (size_t)i * 32;
    const int c0 = (i & 7) * 32;                    // column base within row
    const uint4* cp = (const uint4*)(Cb + base);
    const uint4* ip = (const uint4*)(iden + base);
    uint4 cv[4], iv[4];
#pragma unroll
    for (int q = 0; q < 4; ++q) cv[q] = cp[q];
#pragma unroll
    for (int q = 0; q < 4; ++q) iv[q] = ip[q];

    float dot = 0.f;
    unsigned int qa[8];
    uint4* op = (uint4*)(hout + base);
#pragma unroll
    for (int q = 0; q < 4; ++q) {
        float cf[8], df[8];
        up8(cv[q], cf); up8(iv[q], df);
        const float4 s0 = ((const float4*)(sc + c0 + q * 8))[0];
        const float4 s1 = ((const float4*)(sc + c0 + q * 8))[1];
        const float4 h0 = ((const float4*)(sh + c0 + q * 8))[0];
        const float4 h1 = ((const float4*)(sh + c0 + q * 8))[1];
        float scf[8] = {s0.x, s0.y, s0.z, s0.w, s1.x, s1.y, s1.z, s1.w};
        float shf[8] = {h0.x, h0.y, h0.z, h0.w, h1.x, h1.y, h1.z, h1.w};
        float rbf[8] = {0.f, 0.f, 0.f, 0.f, 0.f, 0.f, 0.f, 0.f};
        if (resb) {
            const float4 r0 = ((const float4*)(resb + c0 + q * 8))[0];
            const float4 r1 = ((const float4*)(resb + c0 + q * 8))[1];
            rbf[0] = r0.x; rbf[1] = r0.y; rbf[2] = r0.z; rbf[3] = r0.w;
            rbf[4] = r1.x; rbf[5] = r1.y; rbf[6] = r1.z; rbf[7] = r1.w;
        }
        float o[8];
#pragma unroll
        for (int e = 0; e < 8; ++e) {
            float v = cf[e] * scf[e] + shf[e];
            o[e] = fmaxf(v, 0.f) + df[e] + rbf[e];
        }
        if (q8out) {
            unsigned int wlo = __builtin_amdgcn_cvt_pk_fp8_f32(o[0], o[1], 0, false);
            wlo = __builtin_amdgcn_cvt_pk_fp8_f32(o[2], o[3], wlo, true);
            unsigned int whi = __builtin_amdgcn_cvt_pk_fp8_f32(o[4], o[5], 0, false);
            whi = __builtin_amdgcn_cvt_pk_fp8_f32(o[6], o[7], whi, true);
            qa[q * 2] = wlo; qa[q * 2 + 1] = whi;
        }
        if (nodedot) {
            const float4 w0 = ((const float4*)(w + c0 + q * 8))[0];
            const float4 w1 = ((const float4*)(w + c0 + q * 8))[1];
            dot += o[0] * w0.x + o[1] * w0.y + o[2] * w0.z + o[3] * w0.w
                 + o[4] * w1.x + o[5] * w1.y + o[6] * w1.z + o[7] * w1.w;
        }
        op[q] = make_uint4(pk2(o[0], o[1]), pk2(o[2], o[3]), pk2(o[4], o[5]), pk2(o[6], o[7]));
    }
    if (q8out) {
        *(uint4*)(q8out + base) = make_uint4(qa[0], qa[1], qa[2], qa[3]);
        *(uint4*)(q8out + base + 16) = make_uint4(qa[4], qa[5], qa[6], qa[7]);
    }
    if (nodedot) {
        dot += __shfl_down(dot, 4);
        dot += __shfl_down(dot, 2);
        dot += __shfl_down(dot, 1);
        if ((threadIdx.x & 7) == 0) nodedot[i >> 3] = dot;
    }
}

// ---------- readout stage 2: one block per graph, contiguous segment sum ----------
__global__ void k_pool(const float* __restrict__ nodedot, const int* __restrict__ gptr,
                       const float* __restrict__ lb, float* __restrict__ out) {
    const int g = blockIdx.x;
    const int r0 = gptr[g], r1 = gptr[g + 1];
    float s = 0.f;
    for (int i = r0 + threadIdx.x; i < r1; i += 256) s += nodedot[i];
#pragma unroll
    for (int off = 32; off > 0; off >>= 1) s += __shfl_down(s, off);
    __shared__ float red[4];
    const int wave = threadIdx.x >> 6;
    if ((threadIdx.x & 63) == 0) red[wave] = s;
    __syncthreads();
    if (threadIdx.x == 0) {
        float tot = red[0] + red[1] + red[2] + red[3];
        int c = r1 - r0; if (c < 1) c = 1;
        out[g] = tot / (float)c + lb[0];
    }
}

extern "C" void kernel_launch(void* const* d_in, const int* in_sizes, int n_in,
                              void* d_out, int out_size, void* d_ws, size_t ws_size,
                              hipStream_t stream) {
    const float* x     = (const float*)d_in[0];
    const int*   ei    = (const int*)d_in[1];
    const int*   batch = (const int*)d_in[2];
    const float* Wl1 = (const float*)d_in[3];
    const float* Wr1 = (const float*)d_in[5];
    const float* g1  = (const float*)d_in[6];
    const float* be1 = (const float*)d_in[7];
    const float* Wl2 = (const float*)d_in[8];
    const float* Wr2 = (const float*)d_in[10];
    const float* g2  = (const float*)d_in[11];
    const float* be2 = (const float*)d_in[12];
    const float* Wl3 = (const float*)d_in[13];
    const float* Wr3 = (const float*)d_in[15];
    const float* g3  = (const float*)d_in[16];
    const float* be3 = (const float*)d_in[17];
    const float* Wl4 = (const float*)d_in[18];
    const float* Wr4 = (const float*)d_in[20];
    const float* g4  = (const float*)d_in[21];
    const float* be4 = (const float*)d_in[22];
    const float* resW = (const float*)d_in[23];
    const float* resb = (const float*)d_in[24];
    const float* linW = (const float*)d_in[25];
    const float* linb = (const float*)d_in[26];
    float* out = (float*)d_out;

    char* p = (char*)d_ws;
    auto carve = [&](size_t bytes) -> char* {
        char* r = p;
        p += (bytes + 255) & ~(size_t)255;
        return r;
    };
    int*   cptr    = (int*)carve((size_t)(N_NODESC + 1) * 4);
    int*   counts  = (int*)carve((size_t)N_NODESC * 4);
    float* dinv    = (float*)carve((size_t)N_NODESC * 4);
    int*   gptr    = (int*)carve((N_GRAPHSC + 1) * 4);
    float* nodedot = (float*)carve((size_t)N_NODESC * 4);
    float* statpart= (float*)carve((size_t)GEMM_NBLK * 256 * 4);
    float* scale   = (float*)carve(256 * 4);
    float* shift   = (float*)carve(256 * 4);
    int*   bsum    = (int*)carve(SCAN_NB * 4);
    int*   boff    = (int*)carve(SCAN_NB * 4);
    int*   adj     = (int*)carve((size_t)N_EDGESC * 4);
    u16*   Wt1     = (u16*)carve(256 * 256 * 2);
    u16*   Wt2     = (u16*)carve(256 * 512 * 2);
    u16*   Wt3     = (u16*)carve(256 * 512 * 2);
    u16*   Wt4     = (u16*)carve(256 * 512 * 2);
    u16*   Rt      = (u16*)carve(256 * 128 * 2);
    u16*   xb      = (u16*)carve((size_t)N_NODESC * F_INC * 2);
    u16*   hA      = (u16*)carve((size_t)N_NODESC * HDIM * 2);
    u16*   hB      = (u16*)carve((size_t)N_NODESC * HDIM * 2);
    u16*   agg     = (u16*)carve((size_t)N_NODESC * HDIM * 2);  // aliased as res for layer 1
    u16*   Cb      = (u16*)carve((size_t)N_NODESC * HDIM * 2);
    unsigned char* q8 = (unsigned char*)carve((size_t)N_NODESC * HDIM); // fp8 gather buffer

    // CSR-build temporaries alias big buffers that are dead during the build:
    unsigned int* P     = (unsigned int*)hA;  // 3.2 MB; dead before hA written (layer-1 finalize)
    unsigned int* epack = (unsigned int*)Cb;  // 6.4 MB; dead before Cb written (layer-1 gemm)
    u16*          Bp    = (u16*)hB;           // 1.6 MB; dead before hB written (layer-2 finalize)
    unsigned char* xb8  = q8;                 // x fp8 (12.8 MB); dead before finalize(1) overwrites q8

    hipMemsetAsync(P, 0, (size_t)8 * N_NODESC * 4, stream);

    const int* srcp = ei;
    const int* dstp = ei + N_EDGESC;

    // weight prep + x conversion (bf16 + fp8)
    k_wcat<<<(256 * 256 + 255) / 256, 256, 0, stream>>>(Wl1, Wr1, 128, 128, Wt1);
    k_wcat<<<(256 * 512 + 255) / 256, 256, 0, stream>>>(Wl2, Wr2, 256, 256, Wt2);
    k_wcat<<<(256 * 512 + 255) / 256, 256, 0, stream>>>(Wl3, Wr3, 256, 256, Wt3);
    k_wcat<<<(256 * 512 + 255) / 256, 256, 0, stream>>>(Wl4, Wr4, 256, 256, Wt4);
    k_wcat<<<(256 * 128 + 255) / 256, 256, 0, stream>>>(resW, resW, 128, 0, Rt);
    k_f2both<<<(N_NODESC * F_INC / 8 + 255) / 256, 256, 0, stream>>>(x, xb, xb8, N_NODESC * F_INC / 8);

    // graph structure (no device-scope atomics anywhere)
    k_gfind<<<5, 64, 0, stream>>>(batch, gptr, N_NODESC);
    k_countP<<<(N_EDGESC + 1023) / 1024, 256, 0, stream>>>(dstp, P, epack, N_EDGESC);
    k_reduceP<<<(N_NODESC + 255) / 256, 256, 0, stream>>>(P, counts, dinv, Bp, N_NODESC);
    k_scan_bsum<<<SCAN_NB, 256, 0, stream>>>(counts, bsum, N_NODESC);
    k_scan_boff<<<1, 256, 0, stream>>>(bsum, boff, SCAN_NB);
    k_scan_write<<<SCAN_NB, 256, 0, stream>>>(counts, boff, cptr, N_NODESC);
    k_fill2<<<(N_EDGESC + 1023) / 1024, 256, 0, stream>>>(srcp, dstp, epack, cptr, Bp, adj, N_EDGESC);

    dim3 gGemm(GEMM_BX, 2);
    const float invN = 1.0f / (float)N_NODESC;
    const int finBlocks = N_NODESC * HDIM / 32 / 256;  // 3125, exact

    // ---- layer 1 ----
    k_aggregate4<128><<<25000, 256, 0, stream>>>(xb8, cptr, adj, dinv, agg, N_NODESC);
    k_gemm<<<gGemm, 256, 0, stream>>>(agg, 128, xb, 128, Wt1, Cb, N_NODESC, statpart);
    k_gemm<<<gGemm, 256, 0, stream>>>(xb, 128, xb, 0, Rt, agg, N_NODESC, nullptr);  // res reuses agg
    k_statbn<<<256, 64, 0, stream>>>(statpart, g1, be1, scale, shift, invN);
    k_finalize2<<<finBlocks, 256, 0, stream>>>(Cb, agg, scale, shift, resb, nullptr, hA, q8, nullptr);

    // ---- layer 2 ----
    k_aggregate4<256><<<25000, 256, 0, stream>>>(q8, cptr, adj, dinv, agg, N_NODESC);
    k_gemm<<<gGemm, 256, 0, stream>>>(agg, 256, hA, 256, Wt2, Cb, N_NODESC, statpart);
    k_statbn<<<256, 64, 0, stream>>>(statpart, g2, be2, scale, shift, invN);
    k_finalize2<<<finBlocks, 256, 0, stream>>>(Cb, hA, scale, shift, nullptr, nullptr, hB, q8, nullptr);

    // ---- layer 3 ----
    k_aggregate4<256><<<25000, 256, 0, stream>>>(q8, cptr, adj, dinv, agg, N_NODESC);
    k_gemm<<<gGemm, 256, 0, stream>>>(agg, 256, hB, 256, Wt3, Cb, N_NODESC, statpart);
    k_statbn<<<256, 64, 0, stream>>>(statpart, g3, be3, scale, shift, invN);
    k_finalize2<<<finBlocks, 256, 0, stream>>>(Cb, hB, scale, shift, nullptr, nullptr, hA, q8, nullptr);

    // ---- layer 4 (fused per-node dot with lin_W; no fp8 needed) ----
    k_aggregate4<256><<<25000, 256, 0, stream>>>(q8, cptr, adj, dinv, agg, N_NODESC);
    k_gemm<<<gGemm, 256, 0, stream>>>(agg, 256, hA, 256, Wt4, Cb, N_NODESC, statpart);
    k_statbn<<<256, 64, 0, stream>>>(statpart, g4, be4, scale, shift, invN);
    k_finalize2<<<finBlocks, 256, 0, stream>>>(Cb, hA, scale, shift, nullptr, linW, hB, nullptr, nodedot);

    // ---- pooled mean + lin_b ----
    k_pool<<<N_GRAPHSC, 256, 0, stream>>>(nodedot, gptr, linb, out);
}

// Round 9
// 939.818 us; speedup vs baseline: 1.2373x; 1.0069x over previous
//
#include <hip/hip_runtime.h>

typedef unsigned short u16;
typedef __attribute__((ext_vector_type(8))) short short8;
typedef __attribute__((ext_vector_type(4))) float floatx4;
typedef __attribute__((ext_vector_type(2))) float floatx2;

#define N_NODESC 100000
#define N_EDGESC 1600000
#define N_GRAPHSC 256
#define F_INC 128
#define HDIM 256
#define SCAN_CHUNK 512
#define SCAN_NB ((N_NODESC + SCAN_CHUNK - 1) / SCAN_CHUNK)  // 196
#define GEMM_BX 782
#define GEMM_NBLK (GEMM_BX * 2)

// async global->LDS DMA, 16B per lane, dest = wave-uniform base + lane*16
#define GLDS16(g, l) __builtin_amdgcn_global_load_lds( \
    (const __attribute__((address_space(1))) unsigned int*)(g), \
    (__attribute__((address_space(3))) unsigned int*)(l), 16, 0, 0)

__device__ __forceinline__ float bf2f(u16 u) {
    union { unsigned int i; float f; } v; v.i = ((unsigned int)u) << 16; return v.f;
}
__device__ __forceinline__ u16 f2bf(float f) {
    union { float f; unsigned int i; } v; v.f = f;
    unsigned int b = v.i;
    b += 0x7fffu + ((b >> 16) & 1u);
    return (u16)(b >> 16);
}
__device__ __forceinline__ void up8(uint4 v, float* f) {
    f[0] = bf2f((u16)(v.x & 0xffff)); f[1] = bf2f((u16)(v.x >> 16));
    f[2] = bf2f((u16)(v.y & 0xffff)); f[3] = bf2f((u16)(v.y >> 16));
    f[4] = bf2f((u16)(v.z & 0xffff)); f[5] = bf2f((u16)(v.z >> 16));
    f[6] = bf2f((u16)(v.w & 0xffff)); f[7] = bf2f((u16)(v.w >> 16));
}
__device__ __forceinline__ unsigned int pk2(float a, float b) {
    return (unsigned int)f2bf(a) | ((unsigned int)f2bf(b) << 16);
}
// accumulate 16 fp8(e4m3) from uint4 into 8 packed float2 accumulators (v_pk_fma_f32)
__device__ __forceinline__ void acc16(uint4 v, float mm, floatx2* a) {
    floatx2 m2 = {mm, mm};
    a[0] += __builtin_amdgcn_cvt_pk_f32_fp8(v.x, false) * m2;
    a[1] += __builtin_amdgcn_cvt_pk_f32_fp8(v.x, true)  * m2;
    a[2] += __builtin_amdgcn_cvt_pk_f32_fp8(v.y, false) * m2;
    a[3] += __builtin_amdgcn_cvt_pk_f32_fp8(v.y, true)  * m2;
    a[4] += __builtin_amdgcn_cvt_pk_f32_fp8(v.z, false) * m2;
    a[5] += __builtin_amdgcn_cvt_pk_f32_fp8(v.z, true)  * m2;
    a[6] += __builtin_amdgcn_cvt_pk_f32_fp8(v.w, false) * m2;
    a[7] += __builtin_amdgcn_cvt_pk_f32_fp8(v.w, true)  * m2;
}
// XCC_ID hwreg (id=20) — measured working on gfx950 (learn_hip m09)
__device__ __forceinline__ int get_xcd() {
    int x;
    asm volatile("s_getreg_b32 %0, hwreg(20, 0, 4)" : "=s"(x));
    return x & 7;
}

// ---------- weight prep: out[c*K + k] = (k<K1 ? Wl[k][c] : Wr[k-K1][c]) as bf16 ----------
__global__ void k_wcat(const float* __restrict__ Wl, const float* __restrict__ Wr,
                       int K1, int K2, u16* __restrict__ out) {
    int K = K1 + K2;
    int idx = blockIdx.x * 256 + threadIdx.x;
    if (idx >= 256 * K) return;
    int c = idx / K, k = idx - c * K;
    float v = (k < K1) ? Wl[k * 256 + c] : Wr[(k - K1) * 256 + c];
    out[idx] = f2bf(v);
}

// ---------- fp32 -> bf16 + fp8 dual convert (8 elems/thread) ----------
__global__ void k_f2both(const float* __restrict__ in, u16* __restrict__ outb,
                         unsigned char* __restrict__ out8, int n8) {
    int i = blockIdx.x * 256 + threadIdx.x;
    if (i >= n8) return;
    float4 v0 = ((const float4*)in)[2 * i];
    float4 v1 = ((const float4*)in)[2 * i + 1];
    ((uint4*)outb)[i] = make_uint4(pk2(v0.x, v0.y), pk2(v0.z, v0.w),
                                   pk2(v1.x, v1.y), pk2(v1.z, v1.w));
    unsigned int wlo = __builtin_amdgcn_cvt_pk_fp8_f32(v0.x, v0.y, 0, false);
    wlo = __builtin_amdgcn_cvt_pk_fp8_f32(v0.z, v0.w, wlo, true);
    unsigned int whi = __builtin_amdgcn_cvt_pk_fp8_f32(v1.x, v1.y, 0, false);
    whi = __builtin_amdgcn_cvt_pk_fp8_f32(v1.z, v1.w, whi, true);
    ((uint2*)out8)[i] = make_uint2(wlo, whi);
}

// ---------- edge count: per-XCD partial histograms, XCD-local (workgroup-scope) atomics ----------
__global__ void k_countP(const int* __restrict__ dst, unsigned int* __restrict__ P,
                         unsigned int* __restrict__ epack, int E) {
    const int xcd = get_xcd();
    unsigned int* Px = P + (size_t)xcd * N_NODESC;
    const int e0 = blockIdx.x * 1024 + threadIdx.x;
#pragma unroll
    for (int l = 0; l < 4; ++l) {
        int e = e0 + l * 256;
        if (e < E) {
            int d = dst[e];
            unsigned int pos = __hip_atomic_fetch_add(&Px[d], 1u, __ATOMIC_RELAXED,
                                                      __HIP_MEMORY_SCOPE_WORKGROUP);
            epack[e] = ((unsigned int)xcd << 16) | pos;
        }
    }
}

// ---------- reduce partials: counts, 1/deg, per-(node,xcd) base offsets ----------
__global__ void k_reduceP(const unsigned int* __restrict__ P, int* __restrict__ counts,
                          float* __restrict__ dinv, u16* __restrict__ Bp, int n) {
    int d = blockIdx.x * 256 + threadIdx.x;
    if (d >= n) return;
    unsigned int s = 0;
    u16 b[8];
#pragma unroll
    for (int x = 0; x < 8; ++x) {
        b[x] = (u16)s;
        s += P[(size_t)x * n + d];
    }
    counts[d] = (int)s;
    dinv[d] = 1.0f / (float)(s > 1u ? s : 1u);
    ushort4* bp = (ushort4*)(Bp + (size_t)d * 8);
    bp[0] = make_ushort4(b[0], b[1], b[2], b[3]);
    bp[1] = make_ushort4(b[4], b[5], b[6], b[7]);
}

// ---------- 3-phase scan over counts -> csr_ptr ----------
__global__ void k_scan_bsum(const int* __restrict__ cnt, int* __restrict__ bsum, int n) {
    __shared__ int ts[256];
    int t = threadIdx.x;
    int i0 = blockIdx.x * SCAN_CHUNK + t * 2;
    int c0 = (i0 < n) ? cnt[i0] : 0;
    int c1 = (i0 + 1 < n) ? cnt[i0 + 1] : 0;
    ts[t] = c0 + c1;
    __syncthreads();
    for (int off = 128; off > 0; off >>= 1) {
        if (t < off) ts[t] += ts[t + off];
        __syncthreads();
    }
    if (t == 0) bsum[blockIdx.x] = ts[0];
}

__global__ void k_scan_boff(const int* __restrict__ bsum, int* __restrict__ boff, int nb) {
    __shared__ int ts[256];
    int t = threadIdx.x;
    int v = (t < nb) ? bsum[t] : 0;
    ts[t] = v;
    __syncthreads();
    for (int off = 1; off < 256; off <<= 1) {
        int u = (t >= off) ? ts[t - off] : 0;
        __syncthreads();
        ts[t] += u;
        __syncthreads();
    }
    if (t < nb) boff[t] = ts[t] - v;  // exclusive
}

__global__ void k_scan_write(const int* __restrict__ cnt, const int* __restrict__ boff,
                             int* __restrict__ cptr, int n) {
    __shared__ int ts[256];
    int t = threadIdx.x;
    int i0 = blockIdx.x * SCAN_CHUNK + t * 2;
    int c0 = (i0 < n) ? cnt[i0] : 0;
    int c1 = (i0 + 1 < n) ? cnt[i0 + 1] : 0;
    int ms = c0 + c1;
    ts[t] = ms;
    __syncthreads();
    for (int off = 1; off < 256; off <<= 1) {
        int u = (t >= off) ? ts[t - off] : 0;
        __syncthreads();
        ts[t] += u;
        __syncthreads();
    }
    int excl = ts[t] - ms + boff[blockIdx.x];
    if (i0 < n) cptr[i0] = excl;
    if (i0 + 1 < n) cptr[i0 + 1] = excl + c0;
    if (i0 == n - 1) cptr[n] = excl + c0;
    else if (i0 + 1 == n - 1) cptr[n] = excl + c0 + c1;
}

// ---------- CSR fill: slot fully determined, zero atomics ----------
__global__ void k_fill2(const int* __restrict__ src, const int* __restrict__ dst,
                        const unsigned int* __restrict__ epack,
                        const int* __restrict__ cptr, const u16* __restrict__ Bp,
                        int* __restrict__ adj, int E) {
    const int e0 = blockIdx.x * 1024 + threadIdx.x;
#pragma unroll
    for (int l = 0; l < 4; ++l) {
        int e = e0 + l * 256;
        if (e < E) {
            int d = dst[e];
            unsigned int pk = epack[e];
            int x = (int)(pk >> 16);
            int pos = (int)(pk & 0xFFFFu);
            adj[cptr[d] + (int)Bp[(size_t)d * 8 + x] + pos] = src[e];
        }
    }
}

// ---------- graph ranges: batch is sorted -> binary search lower bounds ----------
__global__ void k_gfind(const int* __restrict__ batch, int* __restrict__ gptr, int n) {
    int g = blockIdx.x * 64 + threadIdx.x;
    if (g > N_GRAPHSC) return;
    int lo = 0, hi = n;
    while (lo < hi) {
        int mid = (lo + hi) >> 1;
        if (batch[mid] < g) lo = mid + 1; else hi = mid;
    }
    gptr[g] = lo;
}

// ---------- aggregation v5: fp8 gather (16 B/lane), packed-f32 accumulate, bf16 out ----------
template <int F>
__global__ __launch_bounds__(256) void k_aggregate4(
    const unsigned char* __restrict__ q8, const int* __restrict__ cptr,
    const int* __restrict__ adj, const float* __restrict__ di,
    u16* __restrict__ out, int n) {
    constexpr int LPR = F / 16;       // 8 (F=128) or 16 (F=256)
    constexpr int RPI = 64 / LPR;     // 8 or 4 rows per instruction
    const int lane = threadIdx.x & 63;
    const int node = blockIdx.x * 4 + (threadIdx.x >> 6);
    if (node >= n) return;
    const int sub = lane / LPR;       // row-slot
    const int li  = lane % LPR;       // 16B chunk within row
    const int p0 = cptr[node], p1 = cptr[node + 1];
    const float d = di[node];
    const unsigned char* base = q8 + (size_t)li * 16;
    floatx2 a[8];
#pragma unroll
    for (int e = 0; e < 8; ++e) a[e] = (floatx2){0.f, 0.f};

    int j = p0;
    while (j < p1) {
        int take = p1 - j; if (take > 64) take = 64;
        int myidx = (lane < take) ? adj[j + lane] : 0;
        const int ng = (take + RPI - 1) / RPI;
        for (int g0 = 0; g0 < ng; g0 += 4) {
            int sidx[4]; float m[4];
#pragma unroll
            for (int u = 0; u < 4; ++u) {
                int nb = (g0 + u) * RPI + sub;
                sidx[u] = __shfl(myidx, nb & 63);
                m[u] = (nb < take) ? 1.f : 0.f;
            }
            uint4 hv[4];
#pragma unroll
            for (int u = 0; u < 4; ++u)
                hv[u] = *(const uint4*)(base + (size_t)sidx[u] * F);
#pragma unroll
            for (int u = 0; u < 4; ++u) acc16(hv[u], m[u], a);
        }
        j += take;
    }
    // combine row-slot partials
#pragma unroll
    for (int off = LPR; off < 64; off <<= 1)
#pragma unroll
        for (int e = 0; e < 8; ++e) {
            a[e][0] += __shfl_xor(a[e][0], off);
            a[e][1] += __shfl_xor(a[e][1], off);
        }
    if (sub == 0) {
        uint4 o0 = make_uint4(pk2(a[0][0] * d, a[0][1] * d), pk2(a[1][0] * d, a[1][1] * d),
                              pk2(a[2][0] * d, a[2][1] * d), pk2(a[3][0] * d, a[3][1] * d));
        uint4 o1 = make_uint4(pk2(a[4][0] * d, a[4][1] * d), pk2(a[5][0] * d, a[5][1] * d),
                              pk2(a[6][0] * d, a[6][1] * d), pk2(a[7][0] * d, a[7][1] * d));
        *(uint4*)(out + (size_t)node * F + li * 16) = o0;
        *(uint4*)(out + (size_t)node * F + li * 16 + 8) = o1;
    }
}

// ---------- GEMM v2: BK=64, async global_load_lds staging, XOR-swizzled tight LDS ----------
// LDS tile [128][64] u16, chunk (16B = 8 elems) stored at chunk_index ^ (row & 7).
__global__ __launch_bounds__(256, 4) void k_gemm(
    const u16* __restrict__ A1, int K1,
    const u16* __restrict__ A2, int K2,
    const u16* __restrict__ Wt,
    u16* __restrict__ C, int M, float* __restrict__ statpart) {
    const int K = K1 + K2;
    __shared__ __align__(16) u16 Al[128 * 64];
    __shared__ __align__(16) u16 Bl[128 * 64];
    __shared__ float Ssum[2][128];
    __shared__ float Ssq[2][128];
    const int t = threadIdx.x;
    const int lane = t & 63;
    const int wave = t >> 6;
    const int wr = (wave >> 1) * 64, wc = (wave & 1) * 64;
    const int quad = lane >> 4, l15 = lane & 15;
    const int rowBase = blockIdx.x * 128;
    const int colBase = blockIdx.y * 128;
    const bool fastA = (rowBase + 128 <= M);

    floatx4 acc[4][4];
#pragma unroll
    for (int i = 0; i < 4; ++i)
#pragma unroll
        for (int j = 0; j < 4; ++j)
            acc[i][j] = (floatx4){0.f, 0.f, 0.f, 0.f};

    const int rw = wave * 32 + (lane >> 3);  // staging row base (+8 per sub-instr)
    const int lch = lane & 7;                // this lane's LDS chunk slot

    for (int kt = 0; kt < K; kt += 64) {
        const u16* As; int lda, kloc;
        if (kt < K1) { As = A1; lda = K1; kloc = kt; }
        else         { As = A2; lda = K2; kloc = kt - K1; }
        // ---- B stage (always in-bounds): 4 DMA instrs per wave ----
#pragma unroll
        for (int ii = 0; ii < 4; ++ii) {
            const int row = rw + ii * 8;
            const int gc = lch ^ (row & 7);
            GLDS16(Wt + (size_t)(colBase + row) * K + (kt + gc * 8),
                   Bl + (size_t)(wave * 32 + ii * 8) * 64);
        }
        // ---- A stage ----
        if (fastA) {
#pragma unroll
            for (int ii = 0; ii < 4; ++ii) {
                const int row = rw + ii * 8;
                const int gc = lch ^ (row & 7);
                GLDS16(As + (size_t)(rowBase + row) * lda + (kloc + gc * 8),
                       Al + (size_t)(wave * 32 + ii * 8) * 64);
            }
        } else {
#pragma unroll
            for (int ii = 0; ii < 4; ++ii) {
                const int row = rw + ii * 8;
                const int gc = lch ^ (row & 7);
                const int grow = rowBase + row;
                uint4 v = make_uint4(0u, 0u, 0u, 0u);
                if (grow < M) v = *(const uint4*)(As + (size_t)grow * lda + (kloc + gc * 8));
                *(uint4*)(Al + (size_t)row * 64 + lch * 8) = v;
            }
        }
        __syncthreads();
#pragma unroll
        for (int kk = 0; kk < 2; ++kk) {
            const int gcq = kk * 4 + quad;  // global k-chunk this quad consumes
            short8 af[4], bfr[4];
#pragma unroll
            for (int i = 0; i < 4; ++i) {
                const int row = wr + i * 16 + l15;
                af[i] = *(const short8*)(Al + (size_t)row * 64 + ((gcq ^ (row & 7)) * 8));
            }
#pragma unroll
            for (int j = 0; j < 4; ++j) {
                const int row = wc + j * 16 + l15;
                bfr[j] = *(const short8*)(Bl + (size_t)row * 64 + ((gcq ^ (row & 7)) * 8));
            }
#pragma unroll
            for (int i = 0; i < 4; ++i)
#pragma unroll
                for (int j = 0; j < 4; ++j)
                    acc[i][j] = __builtin_amdgcn_mfma_f32_16x16x32_bf16(af[i], bfr[j], acc[i][j], 0, 0, 0);
        }
        __syncthreads();
    }
    // fused column stats (pad rows have zero A -> zero acc, contribute nothing)
    if (statpart) {
#pragma unroll
        for (int j = 0; j < 4; ++j) {
            float s = 0.f, q = 0.f;
#pragma unroll
            for (int i = 0; i < 4; ++i)
#pragma unroll
                for (int r = 0; r < 4; ++r) {
                    float v = acc[i][j][r];
                    s += v; q += v * v;
                }
            s += __shfl_down(s, 32); s += __shfl_down(s, 16);
            q += __shfl_down(q, 32); q += __shfl_down(q, 16);
            if (lane < 16) {
                Ssum[wr >> 6][wc + j * 16 + l15] = s;
                Ssq[wr >> 6][wc + j * 16 + l15] = q;
            }
        }
        __syncthreads();
        if (t < 128) {
            const size_t bid = (size_t)blockIdx.y * GEMM_BX + blockIdx.x;
            statpart[bid * 256 + t] = Ssum[0][t] + Ssum[1][t];
            statpart[bid * 256 + 128 + t] = Ssq[0][t] + Ssq[1][t];
        }
    }
#pragma unroll
    for (int i = 0; i < 4; ++i) {
#pragma unroll
        for (int r = 0; r < 4; ++r) {
            const int row = rowBase + wr + i * 16 + quad * 4 + r;
            if (row < M) {
#pragma unroll
                for (int j = 0; j < 4; ++j) {
                    const int col = colBase + wc + j * 16 + l15;
                    C[(size_t)row * HDIM + col] = f2bf(acc[i][j][r]);
                }
            }
        }
    }
}

// ---------- fused stat reduce + BN scale/shift: one block per column ----------
__global__ void k_statbn(const float* __restrict__ sp, const float* __restrict__ g,
                         const float* __restrict__ beta, float* __restrict__ sc,
                         float* __restrict__ sh, float invN) {
    const int c = blockIdx.x;                        // 0..255
    const size_t base = (size_t)(c >> 7) * GEMM_BX;  // which column-tile
    const int off = c & 127;
    float s = 0.f, q = 0.f;
    for (int bx = threadIdx.x; bx < GEMM_BX; bx += 64) {
        s += sp[(base + bx) * 256 + off];
        q += sp[(base + bx) * 256 + 128 + off];
    }
#pragma unroll
    for (int o = 32; o > 0; o >>= 1) { s += __shfl_down(s, o); q += __shfl_down(q, o); }
    if (threadIdx.x == 0) {
        float mu = s * invN;
        float var = q * invN - mu * mu;
        float k = g[c] * rsqrtf(var + 1e-5f);
        sc[c] = k;
        sh[c] = beta[c] - mu * k;
    }
}

// ---------- h_next = relu(C*scale+shift) + identity (+res_b); fp8 copy; optional dot ----------
__global__ __launch_bounds__(256) void k_finalize2(
    const u16* __restrict__ Cb, const u16* __restrict__ iden,
    const float* __restrict__ sc, const float* __restrict__ sh,
    const float* __restrict__ resb, const float* __restrict__ w,
    u16* __restrict__ hout, unsigned char* __restrict__ q8out,
    float* __restrict__ nodedot) {
    const int i = blockIdx.x * 256 + threadIdx.x;   // tile id, 32 elems each; grid exact
    const size_t base = (size_t)i * 32;
    const int c0 = (i & 7) * 32;                    // column base within row
    const uint4* cp = (const uint4*)(Cb + base);
    const uint4* ip = (const uint4*)(iden + base);
    uint4 cv[4], iv[4];
#pragma unroll
    for (int q = 0; q < 4; ++q) cv[q] = cp[q];
#pragma unroll
    for (int q = 0; q < 4; ++q) iv[q] = ip[q];

    float dot = 0.f;
    unsigned int qa[8];
    uint4* op = (uint4*)(hout + base);
#pragma unroll
    for (int q = 0; q < 4; ++q) {
        float cf[8], df[8];
        up8(cv[q], cf); up8(iv[q], df);
        const float4 s0 = ((const float4*)(sc + c0 + q * 8))[0];
        const float4 s1 = ((const float4*)(sc + c0 + q * 8))[1];
        const float4 h0 = ((const float4*)(sh + c0 + q * 8))[0];
        const float4 h1 = ((const float4*)(sh + c0 + q * 8))[1];
        float scf[8] = {s0.x, s0.y, s0.z, s0.w, s1.x, s1.y, s1.z, s1.w};
        float shf[8] = {h0.x, h0.y, h0.z, h0.w, h1.x, h1.y, h1.z, h1.w};
        float rbf[8] = {0.f, 0.f, 0.f, 0.f, 0.f, 0.f, 0.f, 0.f};
        if (resb) {
            const float4 r0 = ((const float4*)(resb + c0 + q * 8))[0];
            const float4 r1 = ((const float4*)(resb + c0 + q * 8))[1];
            rbf[0] = r0.x; rbf[1] = r0.y; rbf[2] = r0.z; rbf[3] = r0.w;
            rbf[4] = r1.x; rbf[5] = r1.y; rbf[6] = r1.z; rbf[7] = r1.w;
        }
        float o[8];
#pragma unroll
        for (int e = 0; e < 8; ++e) {
            float v = cf[e] * scf[e] + shf[e];
            o[e] = fmaxf(v, 0.f) + df[e] + rbf[e];
        }
        if (q8out) {
            unsigned int wlo = __builtin_amdgcn_cvt_pk_fp8_f32(o[0], o[1], 0, false);
            wlo = __builtin_amdgcn_cvt_pk_fp8_f32(o[2], o[3], wlo, true);
            unsigned int whi = __builtin_amdgcn_cvt_pk_fp8_f32(o[4], o[5], 0, false);
            whi = __builtin_amdgcn_cvt_pk_fp8_f32(o[6], o[7], whi, true);
            qa[q * 2] = wlo; qa[q * 2 + 1] = whi;
        }
        if (nodedot) {
            const float4 w0 = ((const float4*)(w + c0 + q * 8))[0];
            const float4 w1 = ((const float4*)(w + c0 + q * 8))[1];
            dot += o[0] * w0.x + o[1] * w0.y + o[2] * w0.z + o[3] * w0.w
                 + o[4] * w1.x + o[5] * w1.y + o[6] * w1.z + o[7] * w1.w;
        }
        op[q] = make_uint4(pk2(o[0], o[1]), pk2(o[2], o[3]), pk2(o[4], o[5]), pk2(o[6], o[7]));
    }
    if (q8out) {
        *(uint4*)(q8out + base) = make_uint4(qa[0], qa[1], qa[2], qa[3]);
        *(uint4*)(q8out + base + 16) = make_uint4(qa[4], qa[5], qa[6], qa[7]);
    }
    if (nodedot) {
        dot += __shfl_down(dot, 4);
        dot += __shfl_down(dot, 2);
        dot += __shfl_down(dot, 1);
        if ((threadIdx.x & 7) == 0) nodedot[i >> 3] = dot;
    }
}

// ---------- readout stage 2: one block per graph, contiguous segment sum ----------
__global__ void k_pool(const float* __restrict__ nodedot, const int* __restrict__ gptr,
                       const float* __restrict__ lb, float* __restrict__ out) {
    const int g = blockIdx.x;
    const int r0 = gptr[g], r1 = gptr[g + 1];
    float s = 0.f;
    for (int i = r0 + threadIdx.x; i < r1; i += 256) s += nodedot[i];
#pragma unroll
    for (int off = 32; off > 0; off >>= 1) s += __shfl_down(s, off);
    __shared__ float red[4];
    const int wave = threadIdx.x >> 6;
    if ((threadIdx.x & 63) == 0) red[wave] = s;
    __syncthreads();
    if (threadIdx.x == 0) {
        float tot = red[0] + red[1] + red[2] + red[3];
        int c = r1 - r0; if (c < 1) c = 1;
        out[g] = tot / (float)c + lb[0];
    }
}

extern "C" void kernel_launch(void* const* d_in, const int* in_sizes, int n_in,
                              void* d_out, int out_size, void* d_ws, size_t ws_size,
                              hipStream_t stream) {
    const float* x     = (const float*)d_in[0];
    const int*   ei    = (const int*)d_in[1];
    const int*   batch = (const int*)d_in[2];
    const float* Wl1 = (const float*)d_in[3];
    const float* Wr1 = (const float*)d_in[5];
    const float* g1  = (const float*)d_in[6];
    const float* be1 = (const float*)d_in[7];
    const float* Wl2 = (const float*)d_in[8];
    const float* Wr2 = (const float*)d_in[10];
    const float* g2  = (const float*)d_in[11];
    const float* be2 = (const float*)d_in[12];
    const float* Wl3 = (const float*)d_in[13];
    const float* Wr3 = (const float*)d_in[15];
    const float* g3  = (const float*)d_in[16];
    const float* be3 = (const float*)d_in[17];
    const float* Wl4 = (const float*)d_in[18];
    const float* Wr4 = (const float*)d_in[20];
    const float* g4  = (const float*)d_in[21];
    const float* be4 = (const float*)d_in[22];
    const float* resW = (const float*)d_in[23];
    const float* resb = (const float*)d_in[24];
    const float* linW = (const float*)d_in[25];
    const float* linb = (const float*)d_in[26];
    float* out = (float*)d_out;

    char* p = (char*)d_ws;
    auto carve = [&](size_t bytes) -> char* {
        char* r = p;
        p += (bytes + 255) & ~(size_t)255;
        return r;
    };
    int*   cptr    = (int*)carve((size_t)(N_NODESC + 1) * 4);
    int*   counts  = (int*)carve((size_t)N_NODESC * 4);
    float* dinv    = (float*)carve((size_t)N_NODESC * 4);
    int*   gptr    = (int*)carve((N_GRAPHSC + 1) * 4);
    float* nodedot = (float*)carve((size_t)N_NODESC * 4);
    float* statpart= (float*)carve((size_t)GEMM_NBLK * 256 * 4);
    float* scale   = (float*)carve(256 * 4);
    float* shift   = (float*)carve(256 * 4);
    int*   bsum    = (int*)carve(SCAN_NB * 4);
    int*   boff    = (int*)carve(SCAN_NB * 4);
    int*   adj     = (int*)carve((size_t)N_EDGESC * 4);
    u16*   Wt1     = (u16*)carve(256 * 256 * 2);
    u16*   Wt2     = (u16*)carve(256 * 512 * 2);
    u16*   Wt3     = (u16*)carve(256 * 512 * 2);
    u16*   Wt4     = (u16*)carve(256 * 512 * 2);
    u16*   Rt      = (u16*)carve(256 * 128 * 2);
    u16*   xb      = (u16*)carve((size_t)N_NODESC * F_INC * 2);
    u16*   hA      = (u16*)carve((size_t)N_NODESC * HDIM * 2);
    u16*   hB      = (u16*)carve((size_t)N_NODESC * HDIM * 2);
    u16*   agg     = (u16*)carve((size_t)N_NODESC * HDIM * 2);  // aliased as res for layer 1
    u16*   Cb      = (u16*)carve((size_t)N_NODESC * HDIM * 2);
    unsigned char* q8 = (unsigned char*)carve((size_t)N_NODESC * HDIM); // fp8 gather buffer

    // CSR-build temporaries alias big buffers that are dead during the build:
    unsigned int* P     = (unsigned int*)hA;  // 3.2 MB; dead before hA written (layer-1 finalize)
    unsigned int* epack = (unsigned int*)Cb;  // 6.4 MB; dead before Cb written (layer-1 gemm)
    u16*          Bp    = (u16*)hB;           // 1.6 MB; dead before hB written (layer-2 finalize)
    unsigned char* xb8  = q8;                 // x fp8 (12.8 MB); dead before finalize(1) overwrites q8

    hipMemsetAsync(P, 0, (size_t)8 * N_NODESC * 4, stream);

    const int* srcp = ei;
    const int* dstp = ei + N_EDGESC;

    // weight prep + x conversion (bf16 + fp8)
    k_wcat<<<(256 * 256 + 255) / 256, 256, 0, stream>>>(Wl1, Wr1, 128, 128, Wt1);
    k_wcat<<<(256 * 512 + 255) / 256, 256, 0, stream>>>(Wl2, Wr2, 256, 256, Wt2);
    k_wcat<<<(256 * 512 + 255) / 256, 256, 0, stream>>>(Wl3, Wr3, 256, 256, Wt3);
    k_wcat<<<(256 * 512 + 255) / 256, 256, 0, stream>>>(Wl4, Wr4, 256, 256, Wt4);
    k_wcat<<<(256 * 128 + 255) / 256, 256, 0, stream>>>(resW, resW, 128, 0, Rt);
    k_f2both<<<(N_NODESC * F_INC / 8 + 255) / 256, 256, 0, stream>>>(x, xb, xb8, N_NODESC * F_INC / 8);

    // graph structure (no device-scope atomics anywhere)
    k_gfind<<<5, 64, 0, stream>>>(batch, gptr, N_NODESC);
    k_countP<<<(N_EDGESC + 1023) / 1024, 256, 0, stream>>>(dstp, P, epack, N_EDGESC);
    k_reduceP<<<(N_NODESC + 255) / 256, 256, 0, stream>>>(P, counts, dinv, Bp, N_NODESC);
    k_scan_bsum<<<SCAN_NB, 256, 0, stream>>>(counts, bsum, N_NODESC);
    k_scan_boff<<<1, 256, 0, stream>>>(bsum, boff, SCAN_NB);
    k_scan_write<<<SCAN_NB, 256, 0, stream>>>(counts, boff, cptr, N_NODESC);
    k_fill2<<<(N_EDGESC + 1023) / 1024, 256, 0, stream>>>(srcp, dstp, epack, cptr, Bp, adj, N_EDGESC);

    dim3 gGemm(GEMM_BX, 2);
    const float invN = 1.0f / (float)N_NODESC;
    const int finBlocks = N_NODESC * HDIM / 32 / 256;  // 3125, exact

    // ---- layer 1 ----
    k_aggregate4<128><<<25000, 256, 0, stream>>>(xb8, cptr, adj, dinv, agg, N_NODESC);
    k_gemm<<<gGemm, 256, 0, stream>>>(agg, 128, xb, 128, Wt1, Cb, N_NODESC, statpart);
    k_gemm<<<gGemm, 256, 0, stream>>>(xb, 128, xb, 0, Rt, agg, N_NODESC, nullptr);  // res reuses agg
    k_statbn<<<256, 64, 0, stream>>>(statpart, g1, be1, scale, shift, invN);
    k_finalize2<<<finBlocks, 256, 0, stream>>>(Cb, agg, scale, shift, resb, nullptr, hA, q8, nullptr);

    // ---- layer 2 ----
    k_aggregate4<256><<<25000, 256, 0, stream>>>(q8, cptr, adj, dinv, agg, N_NODESC);
    k_gemm<<<gGemm, 256, 0, stream>>>(agg, 256, hA, 256, Wt2, Cb, N_NODESC, statpart);
    k_statbn<<<256, 64, 0, stream>>>(statpart, g2, be2, scale, shift, invN);
    k_finalize2<<<finBlocks, 256, 0, stream>>>(Cb, hA, scale, shift, nullptr, nullptr, hB, q8, nullptr);

    // ---- layer 3 ----
    k_aggregate4<256><<<25000, 256, 0, stream>>>(q8, cptr, adj, dinv, agg, N_NODESC);
    k_gemm<<<gGemm, 256, 0, stream>>>(agg, 256, hB, 256, Wt3, Cb, N_NODESC, statpart);
    k_statbn<<<256, 64, 0, stream>>>(statpart, g3, be3, scale, shift, invN);
    k_finalize2<<<finBlocks, 256, 0, stream>>>(Cb, hB, scale, shift, nullptr, nullptr, hA, q8, nullptr);

    // ---- layer 4 (fused per-node dot with lin_W; no fp8 needed) ----
    k_aggregate4<256><<<25000, 256, 0, stream>>>(q8, cptr, adj, dinv, agg, N_NODESC);
    k_gemm<<<gGemm, 256, 0, stream>>>(agg, 256, hA, 256, Wt4, Cb, N_NODESC, statpart);
    k_statbn<<<256, 64, 0, stream>>>(statpart, g4, be4, scale, shift, invN);
    k_finalize2<<<finBlocks, 256, 0, stream>>>(Cb, hA, scale, shift, nullptr, linW, hB, nullptr, nodedot);

    // ---- pooled mean + lin_b ----
    k_pool<<<N_GRAPHSC, 256, 0, stream>>>(nodedot, gptr, linb, out);
}

// Round 10
// 935.800 us; speedup vs baseline: 1.2426x; 1.0043x over previous
//
#include <hip/hip_runtime.h>

typedef unsigned short u16;
typedef __attribute__((ext_vector_type(8))) short short8;
typedef __attribute__((ext_vector_type(4))) float floatx4;
typedef __attribute__((ext_vector_type(2))) float floatx2;

#define N_NODESC 100000
#define N_EDGESC 1600000
#define N_GRAPHSC 256
#define F_INC 128
#define HDIM 256
#define SCAN_CHUNK 512
#define SCAN_NB ((N_NODESC + SCAN_CHUNK - 1) / SCAN_CHUNK)  // 196
#define GEMM_BX 782
#define GEMM_NBLK (GEMM_BX * 2)

// async global->LDS DMA, 16B per lane, dest = wave-uniform base + lane*16
#define GLDS16(g, l) __builtin_amdgcn_global_load_lds( \
    (const __attribute__((address_space(1))) unsigned int*)(g), \
    (__attribute__((address_space(3))) unsigned int*)(l), 16, 0, 0)

__device__ __forceinline__ float bf2f(u16 u) {
    union { unsigned int i; float f; } v; v.i = ((unsigned int)u) << 16; return v.f;
}
__device__ __forceinline__ u16 f2bf(float f) {
    union { float f; unsigned int i; } v; v.f = f;
    unsigned int b = v.i;
    b += 0x7fffu + ((b >> 16) & 1u);
    return (u16)(b >> 16);
}
__device__ __forceinline__ void up8(uint4 v, float* f) {
    f[0] = bf2f((u16)(v.x & 0xffff)); f[1] = bf2f((u16)(v.x >> 16));
    f[2] = bf2f((u16)(v.y & 0xffff)); f[3] = bf2f((u16)(v.y >> 16));
    f[4] = bf2f((u16)(v.z & 0xffff)); f[5] = bf2f((u16)(v.z >> 16));
    f[6] = bf2f((u16)(v.w & 0xffff)); f[7] = bf2f((u16)(v.w >> 16));
}
__device__ __forceinline__ unsigned int pk2(float a, float b) {
    return (unsigned int)f2bf(a) | ((unsigned int)f2bf(b) << 16);
}
// accumulate 16 fp8(e4m3) from uint4 into 8 packed float2 accumulators (v_pk_fma_f32)
__device__ __forceinline__ void acc16(uint4 v, float mm, floatx2* a) {
    floatx2 m2 = {mm, mm};
    a[0] += __builtin_amdgcn_cvt_pk_f32_fp8(v.x, false) * m2;
    a[1] += __builtin_amdgcn_cvt_pk_f32_fp8(v.x, true)  * m2;
    a[2] += __builtin_amdgcn_cvt_pk_f32_fp8(v.y, false) * m2;
    a[3] += __builtin_amdgcn_cvt_pk_f32_fp8(v.y, true)  * m2;
    a[4] += __builtin_amdgcn_cvt_pk_f32_fp8(v.z, false) * m2;
    a[5] += __builtin_amdgcn_cvt_pk_f32_fp8(v.z, true)  * m2;
    a[6] += __builtin_amdgcn_cvt_pk_f32_fp8(v.w, false) * m2;
    a[7] += __builtin_amdgcn_cvt_pk_f32_fp8(v.w, true)  * m2;
}
// XCC_ID hwreg (id=20) — measured working on gfx950 (learn_hip m09)
__device__ __forceinline__ int get_xcd() {
    int x;
    asm volatile("s_getreg_b32 %0, hwreg(20, 0, 4)" : "=s"(x));
    return x & 7;
}

// ---------- weight prep: out[c*K + k] = (k<K1 ? Wl[k][c] : Wr[k-K1][c]) as bf16 ----------
__global__ void k_wcat(const float* __restrict__ Wl, const float* __restrict__ Wr,
                       int K1, int K2, u16* __restrict__ out) {
    int K = K1 + K2;
    int idx = blockIdx.x * 256 + threadIdx.x;
    if (idx >= 256 * K) return;
    int c = idx / K, k = idx - c * K;
    float v = (k < K1) ? Wl[k * 256 + c] : Wr[(k - K1) * 256 + c];
    out[idx] = f2bf(v);
}

// ---------- fp32 -> bf16 + fp8 dual convert (8 elems/thread) ----------
__global__ void k_f2both(const float* __restrict__ in, u16* __restrict__ outb,
                         unsigned char* __restrict__ out8, int n8) {
    int i = blockIdx.x * 256 + threadIdx.x;
    if (i >= n8) return;
    float4 v0 = ((const float4*)in)[2 * i];
    float4 v1 = ((const float4*)in)[2 * i + 1];
    ((uint4*)outb)[i] = make_uint4(pk2(v0.x, v0.y), pk2(v0.z, v0.w),
                                   pk2(v1.x, v1.y), pk2(v1.z, v1.w));
    unsigned int wlo = __builtin_amdgcn_cvt_pk_fp8_f32(v0.x, v0.y, 0, false);
    wlo = __builtin_amdgcn_cvt_pk_fp8_f32(v0.z, v0.w, wlo, true);
    unsigned int whi = __builtin_amdgcn_cvt_pk_fp8_f32(v1.x, v1.y, 0, false);
    whi = __builtin_amdgcn_cvt_pk_fp8_f32(v1.z, v1.w, whi, true);
    ((uint2*)out8)[i] = make_uint2(wlo, whi);
}

// ---------- edge count: per-XCD partial histograms, XCD-local atomics ----------
// Streaming traffic (dst reads, epack writes) is non-temporal so the Px
// histogram slice stays resident in the XCD's L2 (R9: 50 MB of Px writeback churn).
__global__ void k_countP(const int* __restrict__ dst, unsigned int* __restrict__ P,
                         unsigned int* __restrict__ epack, int E) {
    const int xcd = get_xcd();
    unsigned int* Px = P + (size_t)xcd * N_NODESC;
    const int e0 = blockIdx.x * 1024 + threadIdx.x;
#pragma unroll
    for (int l = 0; l < 4; ++l) {
        int e = e0 + l * 256;
        if (e < E) {
            int d = __builtin_nontemporal_load(&dst[e]);
            unsigned int pos = __hip_atomic_fetch_add(&Px[d], 1u, __ATOMIC_RELAXED,
                                                      __HIP_MEMORY_SCOPE_WORKGROUP);
            __builtin_nontemporal_store(((unsigned int)xcd << 16) | pos, &epack[e]);
        }
    }
}

// ---------- reduce partials: counts, 1/deg, per-(node,xcd) base offsets ----------
__global__ void k_reduceP(const unsigned int* __restrict__ P, int* __restrict__ counts,
                          float* __restrict__ dinv, u16* __restrict__ Bp, int n) {
    int d = blockIdx.x * 256 + threadIdx.x;
    if (d >= n) return;
    unsigned int s = 0;
    u16 b[8];
#pragma unroll
    for (int x = 0; x < 8; ++x) {
        b[x] = (u16)s;
        s += P[(size_t)x * n + d];
    }
    counts[d] = (int)s;
    dinv[d] = 1.0f / (float)(s > 1u ? s : 1u);
    ushort4* bp = (ushort4*)(Bp + (size_t)d * 8);
    bp[0] = make_ushort4(b[0], b[1], b[2], b[3]);
    bp[1] = make_ushort4(b[4], b[5], b[6], b[7]);
}

// ---------- 3-phase scan over counts -> csr_ptr ----------
__global__ void k_scan_bsum(const int* __restrict__ cnt, int* __restrict__ bsum, int n) {
    __shared__ int ts[256];
    int t = threadIdx.x;
    int i0 = blockIdx.x * SCAN_CHUNK + t * 2;
    int c0 = (i0 < n) ? cnt[i0] : 0;
    int c1 = (i0 + 1 < n) ? cnt[i0 + 1] : 0;
    ts[t] = c0 + c1;
    __syncthreads();
    for (int off = 128; off > 0; off >>= 1) {
        if (t < off) ts[t] += ts[t + off];
        __syncthreads();
    }
    if (t == 0) bsum[blockIdx.x] = ts[0];
}

__global__ void k_scan_boff(const int* __restrict__ bsum, int* __restrict__ boff, int nb) {
    __shared__ int ts[256];
    int t = threadIdx.x;
    int v = (t < nb) ? bsum[t] : 0;
    ts[t] = v;
    __syncthreads();
    for (int off = 1; off < 256; off <<= 1) {
        int u = (t >= off) ? ts[t - off] : 0;
        __syncthreads();
        ts[t] += u;
        __syncthreads();
    }
    if (t < nb) boff[t] = ts[t] - v;  // exclusive
}

__global__ void k_scan_write(const int* __restrict__ cnt, const int* __restrict__ boff,
                             int* __restrict__ cptr, int n) {
    __shared__ int ts[256];
    int t = threadIdx.x;
    int i0 = blockIdx.x * SCAN_CHUNK + t * 2;
    int c0 = (i0 < n) ? cnt[i0] : 0;
    int c1 = (i0 + 1 < n) ? cnt[i0 + 1] : 0;
    int ms = c0 + c1;
    ts[t] = ms;
    __syncthreads();
    for (int off = 1; off < 256; off <<= 1) {
        int u = (t >= off) ? ts[t - off] : 0;
        __syncthreads();
        ts[t] += u;
        __syncthreads();
    }
    int excl = ts[t] - ms + boff[blockIdx.x];
    if (i0 < n) cptr[i0] = excl;
    if (i0 + 1 < n) cptr[i0 + 1] = excl + c0;
    if (i0 == n - 1) cptr[n] = excl + c0;
    else if (i0 + 1 == n - 1) cptr[n] = excl + c0 + c1;
}

// ---------- CSR fill: slot fully determined, zero atomics; streams non-temporal ----------
__global__ void k_fill2(const int* __restrict__ src, const int* __restrict__ dst,
                        const unsigned int* __restrict__ epack,
                        const int* __restrict__ cptr, const u16* __restrict__ Bp,
                        int* __restrict__ adj, int E) {
    const int e0 = blockIdx.x * 1024 + threadIdx.x;
#pragma unroll
    for (int l = 0; l < 4; ++l) {
        int e = e0 + l * 256;
        if (e < E) {
            int d = __builtin_nontemporal_load(&dst[e]);
            unsigned int pk = __builtin_nontemporal_load(&epack[e]);
            int s = __builtin_nontemporal_load(&src[e]);
            int x = (int)(pk >> 16);
            int pos = (int)(pk & 0xFFFFu);
            __builtin_nontemporal_store(s, &adj[cptr[d] + (int)Bp[(size_t)d * 8 + x] + pos]);
        }
    }
}

// ---------- graph ranges: batch is sorted -> binary search lower bounds ----------
__global__ void k_gfind(const int* __restrict__ batch, int* __restrict__ gptr, int n) {
    int g = blockIdx.x * 64 + threadIdx.x;
    if (g > N_GRAPHSC) return;
    int lo = 0, hi = n;
    while (lo < hi) {
        int mid = (lo + hi) >> 1;
        if (batch[mid] < g) lo = mid + 1; else hi = mid;
    }
    gptr[g] = lo;
}

// ---------- aggregation v5: fp8 gather (16 B/lane), packed-f32 accumulate, bf16 out ----------
template <int F>
__global__ __launch_bounds__(256) void k_aggregate4(
    const unsigned char* __restrict__ q8, const int* __restrict__ cptr,
    const int* __restrict__ adj, const float* __restrict__ di,
    u16* __restrict__ out, int n) {
    constexpr int LPR = F / 16;       // 8 (F=128) or 16 (F=256)
    constexpr int RPI = 64 / LPR;     // 8 or 4 rows per instruction
    const int lane = threadIdx.x & 63;
    const int node = blockIdx.x * 4 + (threadIdx.x >> 6);
    if (node >= n) return;
    const int sub = lane / LPR;       // row-slot
    const int li  = lane % LPR;       // 16B chunk within row
    const int p0 = cptr[node], p1 = cptr[node + 1];
    const float d = di[node];
    const unsigned char* base = q8 + (size_t)li * 16;
    floatx2 a[8];
#pragma unroll
    for (int e = 0; e < 8; ++e) a[e] = (floatx2){0.f, 0.f};

    int j = p0;
    while (j < p1) {
        int take = p1 - j; if (take > 64) take = 64;
        int myidx = (lane < take) ? adj[j + lane] : 0;
        const int ng = (take + RPI - 1) / RPI;
        for (int g0 = 0; g0 < ng; g0 += 4) {
            int sidx[4]; float m[4];
#pragma unroll
            for (int u = 0; u < 4; ++u) {
                int nb = (g0 + u) * RPI + sub;
                sidx[u] = __shfl(myidx, nb & 63);
                m[u] = (nb < take) ? 1.f : 0.f;
            }
            uint4 hv[4];
#pragma unroll
            for (int u = 0; u < 4; ++u)
                hv[u] = *(const uint4*)(base + (size_t)sidx[u] * F);
#pragma unroll
            for (int u = 0; u < 4; ++u) acc16(hv[u], m[u], a);
        }
        j += take;
    }
    // combine row-slot partials
#pragma unroll
    for (int off = LPR; off < 64; off <<= 1)
#pragma unroll
        for (int e = 0; e < 8; ++e) {
            a[e][0] += __shfl_xor(a[e][0], off);
            a[e][1] += __shfl_xor(a[e][1], off);
        }
    if (sub == 0) {
        uint4 o0 = make_uint4(pk2(a[0][0] * d, a[0][1] * d), pk2(a[1][0] * d, a[1][1] * d),
                              pk2(a[2][0] * d, a[2][1] * d), pk2(a[3][0] * d, a[3][1] * d));
        uint4 o1 = make_uint4(pk2(a[4][0] * d, a[4][1] * d), pk2(a[5][0] * d, a[5][1] * d),
                              pk2(a[6][0] * d, a[6][1] * d), pk2(a[7][0] * d, a[7][1] * d));
        *(uint4*)(out + (size_t)node * F + li * 16) = o0;
        *(uint4*)(out + (size_t)node * F + li * 16 + 8) = o1;
    }
}

// ---------- GEMM v2: BK=64, async global_load_lds staging, XOR-swizzled tight LDS ----------
// LDS tile [128][64] u16, chunk (16B = 8 elems) stored at chunk_index ^ (row & 7).
__global__ __launch_bounds__(256, 4) void k_gemm(
    const u16* __restrict__ A1, int K1,
    const u16* __restrict__ A2, int K2,
    const u16* __restrict__ Wt,
    u16* __restrict__ C, int M, float* __restrict__ statpart) {
    const int K = K1 + K2;
    __shared__ __align__(16) u16 Al[128 * 64];
    __shared__ __align__(16) u16 Bl[128 * 64];
    __shared__ float Ssum[2][128];
    __shared__ float Ssq[2][128];
    const int t = threadIdx.x;
    const int lane = t & 63;
    const int wave = t >> 6;
    const int wr = (wave >> 1) * 64, wc = (wave & 1) * 64;
    const int quad = lane >> 4, l15 = lane & 15;
    const int rowBase = blockIdx.x * 128;
    const int colBase = blockIdx.y * 128;
    const bool fastA = (rowBase + 128 <= M);

    floatx4 acc[4][4];
#pragma unroll
    for (int i = 0; i < 4; ++i)
#pragma unroll
        for (int j = 0; j < 4; ++j)
            acc[i][j] = (floatx4){0.f, 0.f, 0.f, 0.f};

    const int rw = wave * 32 + (lane >> 3);  // staging row base (+8 per sub-instr)
    const int lch = lane & 7;                // this lane's LDS chunk slot

    for (int kt = 0; kt < K; kt += 64) {
        const u16* As; int lda, kloc;
        if (kt < K1) { As = A1; lda = K1; kloc = kt; }
        else         { As = A2; lda = K2; kloc = kt - K1; }
        // ---- B stage (always in-bounds): 4 DMA instrs per wave ----
#pragma unroll
        for (int ii = 0; ii < 4; ++ii) {
            const int row = rw + ii * 8;
            const int gc = lch ^ (row & 7);
            GLDS16(Wt + (size_t)(colBase + row) * K + (kt + gc * 8),
                   Bl + (size_t)(wave * 32 + ii * 8) * 64);
        }
        // ---- A stage ----
        if (fastA) {
#pragma unroll
            for (int ii = 0; ii < 4; ++ii) {
                const int row = rw + ii * 8;
                const int gc = lch ^ (row & 7);
                GLDS16(As + (size_t)(rowBase + row) * lda + (kloc + gc * 8),
                       Al + (size_t)(wave * 32 + ii * 8) * 64);
            }
        } else {
#pragma unroll
            for (int ii = 0; ii < 4; ++ii) {
                const int row = rw + ii * 8;
                const int gc = lch ^ (row & 7);
                const int grow = rowBase + row;
                uint4 v = make_uint4(0u, 0u, 0u, 0u);
                if (grow < M) v = *(const uint4*)(As + (size_t)grow * lda + (kloc + gc * 8));
                *(uint4*)(Al + (size_t)row * 64 + lch * 8) = v;
            }
        }
        __syncthreads();
#pragma unroll
        for (int kk = 0; kk < 2; ++kk) {
            const int gcq = kk * 4 + quad;  // global k-chunk this quad consumes
            short8 af[4], bfr[4];
#pragma unroll
            for (int i = 0; i < 4; ++i) {
                const int row = wr + i * 16 + l15;
                af[i] = *(const short8*)(Al + (size_t)row * 64 + ((gcq ^ (row & 7)) * 8));
            }
#pragma unroll
            for (int j = 0; j < 4; ++j) {
                const int row = wc + j * 16 + l15;
                bfr[j] = *(const short8*)(Bl + (size_t)row * 64 + ((gcq ^ (row & 7)) * 8));
            }
#pragma unroll
            for (int i = 0; i < 4; ++i)
#pragma unroll
                for (int j = 0; j < 4; ++j)
                    acc[i][j] = __builtin_amdgcn_mfma_f32_16x16x32_bf16(af[i], bfr[j], acc[i][j], 0, 0, 0);
        }
        __syncthreads();
    }
    // fused column stats (pad rows have zero A -> zero acc, contribute nothing)
    if (statpart) {
#pragma unroll
        for (int j = 0; j < 4; ++j) {
            float s = 0.f, q = 0.f;
#pragma unroll
            for (int i = 0; i < 4; ++i)
#pragma unroll
                for (int r = 0; r < 4; ++r) {
                    float v = acc[i][j][r];
                    s += v; q += v * v;
                }
            s += __shfl_down(s, 32); s += __shfl_down(s, 16);
            q += __shfl_down(q, 32); q += __shfl_down(q, 16);
            if (lane < 16) {
                Ssum[wr >> 6][wc + j * 16 + l15] = s;
                Ssq[wr >> 6][wc + j * 16 + l15] = q;
            }
        }
        __syncthreads();
        if (t < 128) {
            const size_t bid = (size_t)blockIdx.y * GEMM_BX + blockIdx.x;
            statpart[bid * 256 + t] = Ssum[0][t] + Ssum[1][t];
            statpart[bid * 256 + 128 + t] = Ssq[0][t] + Ssq[1][t];
        }
    }
#pragma unroll
    for (int i = 0; i < 4; ++i) {
#pragma unroll
        for (int r = 0; r < 4; ++r) {
            const int row = rowBase + wr + i * 16 + quad * 4 + r;
            if (row < M) {
#pragma unroll
                for (int j = 0; j < 4; ++j) {
                    const int col = colBase + wc + j * 16 + l15;
                    C[(size_t)row * HDIM + col] = f2bf(acc[i][j][r]);
                }
            }
        }
    }
}

// ---------- fused stat reduce + BN scale/shift: one block per column ----------
__global__ void k_statbn(const float* __restrict__ sp, const float* __restrict__ g,
                         const float* __restrict__ beta, float* __restrict__ sc,
                         float* __restrict__ sh, float invN) {
    const int c = blockIdx.x;                        // 0..255
    const size_t base = (size_t)(c >> 7) * GEMM_BX;  // which column-tile
    const int off = c & 127;
    float s = 0.f, q = 0.f;
    for (int bx = threadIdx.x; bx < GEMM_BX; bx += 64) {
        s += sp[(base + bx) * 256 + off];
        q += sp[(base + bx) * 256 + 128 + off];
    }
#pragma unroll
    for (int o = 32; o > 0; o >>= 1) { s += __shfl_down(s, o); q += __shfl_down(q, o); }
    if (threadIdx.x == 0) {
        float mu = s * invN;
        float var = q * invN - mu * mu;
        float k = g[c] * rsqrtf(var + 1e-5f);
        sc[c] = k;
        sh[c] = beta[c] - mu * k;
    }
}

// ---------- h_next = relu(C*scale+shift) + identity (+res_b); fp8 copy; optional dot ----------
__global__ __launch_bounds__(256) void k_finalize2(
    const u16* __restrict__ Cb, const u16* __restrict__ iden,
    const float* __restrict__ sc, const float* __restrict__ sh,
    const float* __restrict__ resb, const float* __restrict__ w,
    u16* __restrict__ hout, unsigned char* __restrict__ q8out,
    float* __restrict__ nodedot) {
    const int i = blockIdx.x * 256 + threadIdx.x;   // tile id, 32 elems each; grid exact
    const size_t base = (size_t)i * 32;
    const int c0 = (i & 7) * 32;                    // column base within row
    const uint4* cp = (const uint4*)(Cb + base);
    const uint4* ip = (const uint4*)(iden + base);
    uint4 cv[4], iv[4];
#pragma unroll
    for (int q = 0; q < 4; ++q) cv[q] = cp[q];
#pragma unroll
    for (int q = 0; q < 4; ++q) iv[q] = ip[q];

    float dot = 0.f;
    unsigned int qa[8];
    uint4* op = (uint4*)(hout + base);
#pragma unroll
    for (int q = 0; q < 4; ++q) {
        float cf[8], df[8];
        up8(cv[q], cf); up8(iv[q], df);
        const float4 s0 = ((const float4*)(sc + c0 + q * 8))[0];
        const float4 s1 = ((const float4*)(sc + c0 + q * 8))[1];
        const float4 h0 = ((const float4*)(sh + c0 + q * 8))[0];
        const float4 h1 = ((const float4*)(sh + c0 + q * 8))[1];
        float scf[8] = {s0.x, s0.y, s0.z, s0.w, s1.x, s1.y, s1.z, s1.w};
        float shf[8] = {h0.x, h0.y, h0.z, h0.w, h1.x, h1.y, h1.z, h1.w};
        float rbf[8] = {0.f, 0.f, 0.f, 0.f, 0.f, 0.f, 0.f, 0.f};
        if (resb) {
            const float4 r0 = ((const float4*)(resb + c0 + q * 8))[0];
            const float4 r1 = ((const float4*)(resb + c0 + q * 8))[1];
            rbf[0] = r0.x; rbf[1] = r0.y; rbf[2] = r0.z; rbf[3] = r0.w;
            rbf[4] = r1.x; rbf[5] = r1.y; rbf[6] = r1.z; rbf[7] = r1.w;
        }
        float o[8];
#pragma unroll
        for (int e = 0; e < 8; ++e) {
            float v = cf[e] * scf[e] + shf[e];
            o[e] = fmaxf(v, 0.f) + df[e] + rbf[e];
        }
        if (q8out) {
            unsigned int wlo = __builtin_amdgcn_cvt_pk_fp8_f32(o[0], o[1], 0, false);
            wlo = __builtin_amdgcn_cvt_pk_fp8_f32(o[2], o[3], wlo, true);
            unsigned int whi = __builtin_amdgcn_cvt_pk_fp8_f32(o[4], o[5], 0, false);
            whi = __builtin_amdgcn_cvt_pk_fp8_f32(o[6], o[7], whi, true);
            qa[q * 2] = wlo; qa[q * 2 + 1] = whi;
        }
        if (nodedot) {
            const float4 w0 = ((const float4*)(w + c0 + q * 8))[0];
            const float4 w1 = ((const float4*)(w + c0 + q * 8))[1];
            dot += o[0] * w0.x + o[1] * w0.y + o[2] * w0.z + o[3] * w0.w
                 + o[4] * w1.x + o[5] * w1.y + o[6] * w1.z + o[7] * w1.w;
        }
        op[q] = make_uint4(pk2(o[0], o[1]), pk2(o[2], o[3]), pk2(o[4], o[5]), pk2(o[6], o[7]));
    }
    if (q8out) {
        *(uint4*)(q8out + base) = make_uint4(qa[0], qa[1], qa[2], qa[3]);
        *(uint4*)(q8out + base + 16) = make_uint4(qa[4], qa[5], qa[6], qa[7]);
    }
    if (nodedot) {
        dot += __shfl_down(dot, 4);
        dot += __shfl_down(dot, 2);
        dot += __shfl_down(dot, 1);
        if ((threadIdx.x & 7) == 0) nodedot[i >> 3] = dot;
    }
}

// ---------- readout stage 2: one block per graph, contiguous segment sum ----------
__global__ void k_pool(const float* __restrict__ nodedot, const int* __restrict__ gptr,
                       const float* __restrict__ lb, float* __restrict__ out) {
    const int g = blockIdx.x;
    const int r0 = gptr[g], r1 = gptr[g + 1];
    float s = 0.f;
    for (int i = r0 + threadIdx.x; i < r1; i += 256) s += nodedot[i];
#pragma unroll
    for (int off = 32; off > 0; off >>= 1) s += __shfl_down(s, off);
    __shared__ float red[4];
    const int wave = threadIdx.x >> 6;
    if ((threadIdx.x & 63) == 0) red[wave] = s;
    __syncthreads();
    if (threadIdx.x == 0) {
        float tot = red[0] + red[1] + red[2] + red[3];
        int c = r1 - r0; if (c < 1) c = 1;
        out[g] = tot / (float)c + lb[0];
    }
}

extern "C" void kernel_launch(void* const* d_in, const int* in_sizes, int n_in,
                              void* d_out, int out_size, void* d_ws, size_t ws_size,
                              hipStream_t stream) {
    const float* x     = (const float*)d_in[0];
    const int*   ei    = (const int*)d_in[1];
    const int*   batch = (const int*)d_in[2];
    const float* Wl1 = (const float*)d_in[3];
    const float* Wr1 = (const float*)d_in[5];
    const float* g1  = (const float*)d_in[6];
    const float* be1 = (const float*)d_in[7];
    const float* Wl2 = (const float*)d_in[8];
    const float* Wr2 = (const float*)d_in[10];
    const float* g2  = (const float*)d_in[11];
    const float* be2 = (const float*)d_in[12];
    const float* Wl3 = (const float*)d_in[13];
    const float* Wr3 = (const float*)d_in[15];
    const float* g3  = (const float*)d_in[16];
    const float* be3 = (const float*)d_in[17];
    const float* Wl4 = (const float*)d_in[18];
    const float* Wr4 = (const float*)d_in[20];
    const float* g4  = (const float*)d_in[21];
    const float* be4 = (const float*)d_in[22];
    const float* resW = (const float*)d_in[23];
    const float* resb = (const float*)d_in[24];
    const float* linW = (const float*)d_in[25];
    const float* linb = (const float*)d_in[26];
    float* out = (float*)d_out;

    char* p = (char*)d_ws;
    auto carve = [&](size_t bytes) -> char* {
        char* r = p;
        p += (bytes + 255) & ~(size_t)255;
        return r;
    };
    int*   cptr    = (int*)carve((size_t)(N_NODESC + 1) * 4);
    int*   counts  = (int*)carve((size_t)N_NODESC * 4);
    float* dinv    = (float*)carve((size_t)N_NODESC * 4);
    int*   gptr    = (int*)carve((N_GRAPHSC + 1) * 4);
    float* nodedot = (float*)carve((size_t)N_NODESC * 4);
    float* statpart= (float*)carve((size_t)GEMM_NBLK * 256 * 4);
    float* scale   = (float*)carve(256 * 4);
    float* shift   = (float*)carve(256 * 4);
    int*   bsum    = (int*)carve(SCAN_NB * 4);
    int*   boff    = (int*)carve(SCAN_NB * 4);
    int*   adj     = (int*)carve((size_t)N_EDGESC * 4);
    u16*   Wt1     = (u16*)carve(256 * 256 * 2);
    u16*   Wt2     = (u16*)carve(256 * 512 * 2);
    u16*   Wt3     = (u16*)carve(256 * 512 * 2);
    u16*   Wt4     = (u16*)carve(256 * 512 * 2);
    u16*   Rt      = (u16*)carve(256 * 128 * 2);
    u16*   xb      = (u16*)carve((size_t)N_NODESC * F_INC * 2);
    u16*   hA      = (u16*)carve((size_t)N_NODESC * HDIM * 2);
    u16*   hB      = (u16*)carve((size_t)N_NODESC * HDIM * 2);
    u16*   agg     = (u16*)carve((size_t)N_NODESC * HDIM * 2);  // aliased as res for layer 1
    u16*   Cb      = (u16*)carve((size_t)N_NODESC * HDIM * 2);
    unsigned char* q8 = (unsigned char*)carve((size_t)N_NODESC * HDIM); // fp8 gather buffer

    // CSR-build temporaries alias big buffers that are dead during the build:
    unsigned int* P     = (unsigned int*)hA;  // 3.2 MB; dead before hA written (layer-1 finalize)
    unsigned int* epack = (unsigned int*)Cb;  // 6.4 MB; dead before Cb written (layer-1 gemm)
    u16*          Bp    = (u16*)hB;           // 1.6 MB; dead before hB written (layer-2 finalize)
    unsigned char* xb8  = q8;                 // x fp8 (12.8 MB); dead before finalize(1) overwrites q8

    hipMemsetAsync(P, 0, (size_t)8 * N_NODESC * 4, stream);

    const int* srcp = ei;
    const int* dstp = ei + N_EDGESC;

    // weight prep + x conversion (bf16 + fp8)
    k_wcat<<<(256 * 256 + 255) / 256, 256, 0, stream>>>(Wl1, Wr1, 128, 128, Wt1);
    k_wcat<<<(256 * 512 + 255) / 256, 256, 0, stream>>>(Wl2, Wr2, 256, 256, Wt2);
    k_wcat<<<(256 * 512 + 255) / 256, 256, 0, stream>>>(Wl3, Wr3, 256, 256, Wt3);
    k_wcat<<<(256 * 512 + 255) / 256, 256, 0, stream>>>(Wl4, Wr4, 256, 256, Wt4);
    k_wcat<<<(256 * 128 + 255) / 256, 256, 0, stream>>>(resW, resW, 128, 0, Rt);
    k_f2both<<<(N_NODESC * F_INC / 8 + 255) / 256, 256, 0, stream>>>(x, xb, xb8, N_NODESC * F_INC / 8);

    // graph structure (no device-scope atomics anywhere)
    k_gfind<<<5, 64, 0, stream>>>(batch, gptr, N_NODESC);
    k_countP<<<(N_EDGESC + 1023) / 1024, 256, 0, stream>>>(dstp, P, epack, N_EDGESC);
    k_reduceP<<<(N_NODESC + 255) / 256, 256, 0, stream>>>(P, counts, dinv, Bp, N_NODESC);
    k_scan_bsum<<<SCAN_NB, 256, 0, stream>>>(counts, bsum, N_NODESC);
    k_scan_boff<<<1, 256, 0, stream>>>(bsum, boff, SCAN_NB);
    k_scan_write<<<SCAN_NB, 256, 0, stream>>>(counts, boff, cptr, N_NODESC);
    k_fill2<<<(N_EDGESC + 1023) / 1024, 256, 0, stream>>>(srcp, dstp, epack, cptr, Bp, adj, N_EDGESC);

    dim3 gGemm(GEMM_BX, 2);
    const float invN = 1.0f / (float)N_NODESC;
    const int finBlocks = N_NODESC * HDIM / 32 / 256;  // 3125, exact

    // ---- layer 1 ----
    k_aggregate4<128><<<25000, 256, 0, stream>>>(xb8, cptr, adj, dinv, agg, N_NODESC);
    k_gemm<<<gGemm, 256, 0, stream>>>(agg, 128, xb, 128, Wt1, Cb, N_NODESC, statpart);
    k_gemm<<<gGemm, 256, 0, stream>>>(xb, 128, xb, 0, Rt, agg, N_NODESC, nullptr);  // res reuses agg
    k_statbn<<<256, 64, 0, stream>>>(statpart, g1, be1, scale, shift, invN);
    k_finalize2<<<finBlocks, 256, 0, stream>>>(Cb, agg, scale, shift, resb, nullptr, hA, q8, nullptr);

    // ---- layer 2 ----
    k_aggregate4<256><<<25000, 256, 0, stream>>>(q8, cptr, adj, dinv, agg, N_NODESC);
    k_gemm<<<gGemm, 256, 0, stream>>>(agg, 256, hA, 256, Wt2, Cb, N_NODESC, statpart);
    k_statbn<<<256, 64, 0, stream>>>(statpart, g2, be2, scale, shift, invN);
    k_finalize2<<<finBlocks, 256, 0, stream>>>(Cb, hA, scale, shift, nullptr, nullptr, hB, q8, nullptr);

    // ---- layer 3 ----
    k_aggregate4<256><<<25000, 256, 0, stream>>>(q8, cptr, adj, dinv, agg, N_NODESC);
    k_gemm<<<gGemm, 256, 0, stream>>>(agg, 256, hB, 256, Wt3, Cb, N_NODESC, statpart);
    k_statbn<<<256, 64, 0, stream>>>(statpart, g3, be3, scale, shift, invN);
    k_finalize2<<<finBlocks, 256, 0, stream>>>(Cb, hB, scale, shift, nullptr, nullptr, hA, q8, nullptr);

    // ---- layer 4 (fused per-node dot with lin_W; no fp8 needed) ----
    k_aggregate4<256><<<25000, 256, 0, stream>>>(q8, cptr, adj, dinv, agg, N_NODESC);
    k_gemm<<<gGemm, 256, 0, stream>>>(agg, 256, hA, 256, Wt4, Cb, N_NODESC, statpart);
    k_statbn<<<256, 64, 0, stream>>>(statpart, g4, be4, scale, shift, invN);
    k_finalize2<<<finBlocks, 256, 0, stream>>>(Cb, hA, scale, shift, nullptr, linW, hB, nullptr, nodedot);

    // ---- pooled mean + lin_b ----
    k_pool<<<N_GRAPHSC, 256, 0, stream>>>(nodedot, gptr, linb, out);
}

// Round 11
// 857.412 us; speedup vs baseline: 1.3562x; 1.0914x over previous
//
#include <hip/hip_runtime.h>

typedef unsigned short u16;
typedef __attribute__((ext_vector_type(8))) short short8;
typedef __attribute__((ext_vector_type(4))) float floatx4;
typedef __attribute__((ext_vector_type(2))) float floatx2;

#define N_NODESC 100000
#define N_EDGESC 1600000
#define N_GRAPHSC 256
#define F_INC 128
#define HDIM 256
#define GEMM_BX 782
#define GEMM_NBLK (GEMM_BX * 2)
#define RX_NBLK 512
#define RX_EPB (N_EDGESC / RX_NBLK)   // 3125 exact
#define RX_NBUCKET 196                 // ceil(100000/512)

// async global->LDS DMA, 16B per lane, dest = wave-uniform base + lane*16
#define GLDS16(g, l) __builtin_amdgcn_global_load_lds( \
    (const __attribute__((address_space(1))) unsigned int*)(g), \
    (__attribute__((address_space(3))) unsigned int*)(l), 16, 0, 0)

__device__ __forceinline__ float bf2f(u16 u) {
    union { unsigned int i; float f; } v; v.i = ((unsigned int)u) << 16; return v.f;
}
__device__ __forceinline__ u16 f2bf(float f) {
    union { float f; unsigned int i; } v; v.f = f;
    unsigned int b = v.i;
    b += 0x7fffu + ((b >> 16) & 1u);
    return (u16)(b >> 16);
}
__device__ __forceinline__ void up8(uint4 v, float* f) {
    f[0] = bf2f((u16)(v.x & 0xffff)); f[1] = bf2f((u16)(v.x >> 16));
    f[2] = bf2f((u16)(v.y & 0xffff)); f[3] = bf2f((u16)(v.y >> 16));
    f[4] = bf2f((u16)(v.z & 0xffff)); f[5] = bf2f((u16)(v.z >> 16));
    f[6] = bf2f((u16)(v.w & 0xffff)); f[7] = bf2f((u16)(v.w >> 16));
}
__device__ __forceinline__ unsigned int pk2(float a, float b) {
    return (unsigned int)f2bf(a) | ((unsigned int)f2bf(b) << 16);
}
// accumulate 16 fp8(e4m3) from uint4 into 8 packed float2 accumulators (v_pk_fma_f32)
__device__ __forceinline__ void acc16(uint4 v, float mm, floatx2* a) {
    floatx2 m2 = {mm, mm};
    a[0] += __builtin_amdgcn_cvt_pk_f32_fp8(v.x, false) * m2;
    a[1] += __builtin_amdgcn_cvt_pk_f32_fp8(v.x, true)  * m2;
    a[2] += __builtin_amdgcn_cvt_pk_f32_fp8(v.y, false) * m2;
    a[3] += __builtin_amdgcn_cvt_pk_f32_fp8(v.y, true)  * m2;
    a[4] += __builtin_amdgcn_cvt_pk_f32_fp8(v.z, false) * m2;
    a[5] += __builtin_amdgcn_cvt_pk_f32_fp8(v.z, true)  * m2;
    a[6] += __builtin_amdgcn_cvt_pk_f32_fp8(v.w, false) * m2;
    a[7] += __builtin_amdgcn_cvt_pk_f32_fp8(v.w, true)  * m2;
}

// ---------- weight prep: out[c*K + k] = (k<K1 ? Wl[k][c] : Wr[k-K1][c]) as bf16 ----------
__global__ void k_wcat(const float* __restrict__ Wl, const float* __restrict__ Wr,
                       int K1, int K2, u16* __restrict__ out) {
    int K = K1 + K2;
    int idx = blockIdx.x * 256 + threadIdx.x;
    if (idx >= 256 * K) return;
    int c = idx / K, k = idx - c * K;
    float v = (k < K1) ? Wl[k * 256 + c] : Wr[(k - K1) * 256 + c];
    out[idx] = f2bf(v);
}

// ---------- fp32 -> bf16 + fp8 dual convert (8 elems/thread) ----------
__global__ void k_f2both(const float* __restrict__ in, u16* __restrict__ outb,
                         unsigned char* __restrict__ out8, int n8) {
    int i = blockIdx.x * 256 + threadIdx.x;
    if (i >= n8) return;
    float4 v0 = ((const float4*)in)[2 * i];
    float4 v1 = ((const float4*)in)[2 * i + 1];
    ((uint4*)outb)[i] = make_uint4(pk2(v0.x, v0.y), pk2(v0.z, v0.w),
                                   pk2(v1.x, v1.y), pk2(v1.z, v1.w));
    unsigned int wlo = __builtin_amdgcn_cvt_pk_fp8_f32(v0.x, v0.y, 0, false);
    wlo = __builtin_amdgcn_cvt_pk_fp8_f32(v0.z, v0.w, wlo, true);
    unsigned int whi = __builtin_amdgcn_cvt_pk_fp8_f32(v1.x, v1.y, 0, false);
    whi = __builtin_amdgcn_cvt_pk_fp8_f32(v1.z, v1.w, whi, true);
    ((uint2*)out8)[i] = make_uint2(wlo, whi);
}

// ========== CSR build via bucketed counting sort — LDS atomics only ==========
// Pass 1: per-block LDS histogram of dst>>9 -> bhist[block][bucket]
__global__ __launch_bounds__(256) void k_rxcount(const int* __restrict__ dst,
                                                 int* __restrict__ bhist) {
    __shared__ int h[RX_NBUCKET];
    for (int i = threadIdx.x; i < RX_NBUCKET; i += 256) h[i] = 0;
    __syncthreads();
    const int e0 = blockIdx.x * RX_EPB;
    for (int e = e0 + threadIdx.x; e < e0 + RX_EPB; e += 256)
        atomicAdd(&h[dst[e] >> 9], 1);
    __syncthreads();
    for (int i = threadIdx.x; i < RX_NBUCKET; i += 256)
        bhist[blockIdx.x * RX_NBUCKET + i] = h[i];
}

// Pass 2a: per-bucket exclusive prefix over blocks (in-place) + bucket totals
__global__ void k_rxscan1(int* __restrict__ bhist, int* __restrict__ btot) {
    const int k = blockIdx.x;   // bucket
    const int t = threadIdx.x;  // 0..63
    int v[RX_NBLK / 64];
    int s = 0;
#pragma unroll
    for (int i = 0; i < RX_NBLK / 64; ++i) {
        v[i] = bhist[(t * (RX_NBLK / 64) + i) * RX_NBUCKET + k];
        s += v[i];
    }
    int incl = s;
#pragma unroll
    for (int off = 1; off < 64; off <<= 1) {
        int u = __shfl_up(incl, off);
        if (t >= off) incl += u;
    }
    int run = incl - s;  // exclusive
#pragma unroll
    for (int i = 0; i < RX_NBLK / 64; ++i) {
        bhist[(t * (RX_NBLK / 64) + i) * RX_NBUCKET + k] = run;
        run += v[i];
    }
    if (t == 63) btot[k] = run;
}

// Pass 2b: exclusive scan of bucket totals -> bex[197]; also cptr[N]=E
__global__ void k_rxscan2(const int* __restrict__ btot, int* __restrict__ bex,
                          int* __restrict__ cptr) {
    __shared__ int ts[256];
    int t = threadIdx.x;
    int v = (t < RX_NBUCKET) ? btot[t] : 0;
    ts[t] = v;
    __syncthreads();
    for (int off = 1; off < 256; off <<= 1) {
        int u = (t >= off) ? ts[t - off] : 0;
        __syncthreads();
        ts[t] += u;
        __syncthreads();
    }
    if (t < RX_NBUCKET) bex[t] = ts[t] - v;
    if (t == RX_NBUCKET - 1) bex[RX_NBUCKET] = ts[t];
    if (t == 0) cptr[N_NODESC] = N_EDGESC;
}

// Pass 3: scatter (src,dst) pairs into bucket-partitioned ebuf (LDS-atomic ranks)
__global__ __launch_bounds__(256) void k_rxscatter(
    const int* __restrict__ src, const int* __restrict__ dst,
    const int* __restrict__ bhist, const int* __restrict__ bex,
    int2* __restrict__ ebuf) {
    __shared__ int lb[RX_NBUCKET];
    for (int i = threadIdx.x; i < RX_NBUCKET; i += 256)
        lb[i] = bex[i] + bhist[blockIdx.x * RX_NBUCKET + i];
    __syncthreads();
    const int e0 = blockIdx.x * RX_EPB;
    for (int e = e0 + threadIdx.x; e < e0 + RX_EPB; e += 256) {
        int d = dst[e];
        int s = src[e];
        int pos = atomicAdd(&lb[d >> 9], 1);
        ebuf[pos] = make_int2(s, d);
    }
}

// Pass 4: per-bucket CSR: counts -> scan -> cptr/dinv -> adj (LDS atomics)
__global__ __launch_bounds__(256) void k_rxcsr(
    const int2* __restrict__ ebuf, const int* __restrict__ bex,
    int* __restrict__ cptr, float* __restrict__ dinv, int* __restrict__ adj) {
    __shared__ int cnt[512];
    __shared__ int excl[512];
    __shared__ int ts[256];
    const int k = blockIdx.x;
    const int nb0 = k * 512;
    const int ebase = bex[k], eend = bex[k + 1];
    const int t = threadIdx.x;
    for (int i = t; i < 512; i += 256) cnt[i] = 0;
    __syncthreads();
    for (int e = ebase + t; e < eend; e += 256)
        atomicAdd(&cnt[ebuf[e].y - nb0], 1);
    __syncthreads();
    {
        int c0 = cnt[2 * t], c1 = cnt[2 * t + 1];
        int ms = c0 + c1;
        ts[t] = ms;
        __syncthreads();
        for (int off = 1; off < 256; off <<= 1) {
            int u = (t >= off) ? ts[t - off] : 0;
            __syncthreads();
            ts[t] += u;
            __syncthreads();
        }
        int ex = ts[t] - ms;
        excl[2 * t] = ex;
        excl[2 * t + 1] = ex + c0;
        int n0 = nb0 + 2 * t, n1 = n0 + 1;
        if (n0 < N_NODESC) { cptr[n0] = ebase + ex; dinv[n0] = 1.f / (float)(c0 > 1 ? c0 : 1); }
        if (n1 < N_NODESC) { cptr[n1] = ebase + ex + c0; dinv[n1] = 1.f / (float)(c1 > 1 ? c1 : 1); }
    }
    __syncthreads();
    for (int i = t; i < 512; i += 256) cnt[i] = 0;
    __syncthreads();
    for (int e = ebase + t; e < eend; e += 256) {
        int2 p = ebuf[e];
        int dl = p.y - nb0;
        int r = atomicAdd(&cnt[dl], 1);
        adj[ebase + excl[dl] + r] = p.x;
    }
}

// ---------- graph ranges: batch is sorted -> binary search lower bounds ----------
__global__ void k_gfind(const int* __restrict__ batch, int* __restrict__ gptr, int n) {
    int g = blockIdx.x * 64 + threadIdx.x;
    if (g > N_GRAPHSC) return;
    int lo = 0, hi = n;
    while (lo < hi) {
        int mid = (lo + hi) >> 1;
        if (batch[mid] < g) lo = mid + 1; else hi = mid;
    }
    gptr[g] = lo;
}

// ---------- aggregation v5: fp8 gather (16 B/lane), packed-f32 accumulate, bf16 out ----------
template <int F>
__global__ __launch_bounds__(256) void k_aggregate4(
    const unsigned char* __restrict__ q8, const int* __restrict__ cptr,
    const int* __restrict__ adj, const float* __restrict__ di,
    u16* __restrict__ out, int n) {
    constexpr int LPR = F / 16;       // 8 (F=128) or 16 (F=256)
    constexpr int RPI = 64 / LPR;     // 8 or 4 rows per instruction
    const int lane = threadIdx.x & 63;
    const int node = blockIdx.x * 4 + (threadIdx.x >> 6);
    if (node >= n) return;
    const int sub = lane / LPR;       // row-slot
    const int li  = lane % LPR;       // 16B chunk within row
    const int p0 = cptr[node], p1 = cptr[node + 1];
    const float d = di[node];
    const unsigned char* base = q8 + (size_t)li * 16;
    floatx2 a[8];
#pragma unroll
    for (int e = 0; e < 8; ++e) a[e] = (floatx2){0.f, 0.f};

    int j = p0;
    while (j < p1) {
        int take = p1 - j; if (take > 64) take = 64;
        int myidx = (lane < take) ? adj[j + lane] : 0;
        const int ng = (take + RPI - 1) / RPI;
        for (int g0 = 0; g0 < ng; g0 += 4) {
            int sidx[4]; float m[4];
#pragma unroll
            for (int u = 0; u < 4; ++u) {
                int nb = (g0 + u) * RPI + sub;
                sidx[u] = __shfl(myidx, nb & 63);
                m[u] = (nb < take) ? 1.f : 0.f;
            }
            uint4 hv[4];
#pragma unroll
            for (int u = 0; u < 4; ++u)
                hv[u] = *(const uint4*)(base + (size_t)sidx[u] * F);
#pragma unroll
            for (int u = 0; u < 4; ++u) acc16(hv[u], m[u], a);
        }
        j += take;
    }
#pragma unroll
    for (int off = LPR; off < 64; off <<= 1)
#pragma unroll
        for (int e = 0; e < 8; ++e) {
            a[e][0] += __shfl_xor(a[e][0], off);
            a[e][1] += __shfl_xor(a[e][1], off);
        }
    if (sub == 0) {
        uint4 o0 = make_uint4(pk2(a[0][0] * d, a[0][1] * d), pk2(a[1][0] * d, a[1][1] * d),
                              pk2(a[2][0] * d, a[2][1] * d), pk2(a[3][0] * d, a[3][1] * d));
        uint4 o1 = make_uint4(pk2(a[4][0] * d, a[4][1] * d), pk2(a[5][0] * d, a[5][1] * d),
                              pk2(a[6][0] * d, a[6][1] * d), pk2(a[7][0] * d, a[7][1] * d));
        *(uint4*)(out + (size_t)node * F + li * 16) = o0;
        *(uint4*)(out + (size_t)node * F + li * 16 + 8) = o1;
    }
}

// ---------- GEMM v2: BK=64, async global_load_lds staging, XOR-swizzled tight LDS ----------
__global__ __launch_bounds__(256, 4) void k_gemm(
    const u16* __restrict__ A1, int K1,
    const u16* __restrict__ A2, int K2,
    const u16* __restrict__ Wt,
    u16* __restrict__ C, int M, float* __restrict__ statpart) {
    const int K = K1 + K2;
    __shared__ __align__(16) u16 Al[128 * 64];
    __shared__ __align__(16) u16 Bl[128 * 64];
    __shared__ float Ssum[2][128];
    __shared__ float Ssq[2][128];
    const int t = threadIdx.x;
    const int lane = t & 63;
    const int wave = t >> 6;
    const int wr = (wave >> 1) * 64, wc = (wave & 1) * 64;
    const int quad = lane >> 4, l15 = lane & 15;
    const int rowBase = blockIdx.x * 128;
    const int colBase = blockIdx.y * 128;
    const bool fastA = (rowBase + 128 <= M);

    floatx4 acc[4][4];
#pragma unroll
    for (int i = 0; i < 4; ++i)
#pragma unroll
        for (int j = 0; j < 4; ++j)
            acc[i][j] = (floatx4){0.f, 0.f, 0.f, 0.f};

    const int rw = wave * 32 + (lane >> 3);
    const int lch = lane & 7;

    for (int kt = 0; kt < K; kt += 64) {
        const u16* As; int lda, kloc;
        if (kt < K1) { As = A1; lda = K1; kloc = kt; }
        else         { As = A2; lda = K2; kloc = kt - K1; }
#pragma unroll
        for (int ii = 0; ii < 4; ++ii) {
            const int row = rw + ii * 8;
            const int gc = lch ^ (row & 7);
            GLDS16(Wt + (size_t)(colBase + row) * K + (kt + gc * 8),
                   Bl + (size_t)(wave * 32 + ii * 8) * 64);
        }
        if (fastA) {
#pragma unroll
            for (int ii = 0; ii < 4; ++ii) {
                const int row = rw + ii * 8;
                const int gc = lch ^ (row & 7);
                GLDS16(As + (size_t)(rowBase + row) * lda + (kloc + gc * 8),
                       Al + (size_t)(wave * 32 + ii * 8) * 64);
            }
        } else {
#pragma unroll
            for (int ii = 0; ii < 4; ++ii) {
                const int row = rw + ii * 8;
                const int gc = lch ^ (row & 7);
                const int grow = rowBase + row;
                uint4 v = make_uint4(0u, 0u, 0u, 0u);
                if (grow < M) v = *(const uint4*)(As + (size_t)grow * lda + (kloc + gc * 8));
                *(uint4*)(Al + (size_t)row * 64 + lch * 8) = v;
            }
        }
        __syncthreads();
#pragma unroll
        for (int kk = 0; kk < 2; ++kk) {
            const int gcq = kk * 4 + quad;
            short8 af[4], bfr[4];
#pragma unroll
            for (int i = 0; i < 4; ++i) {
                const int row = wr + i * 16 + l15;
                af[i] = *(const short8*)(Al + (size_t)row * 64 + ((gcq ^ (row & 7)) * 8));
            }
#pragma unroll
            for (int j = 0; j < 4; ++j) {
                const int row = wc + j * 16 + l15;
                bfr[j] = *(const short8*)(Bl + (size_t)row * 64 + ((gcq ^ (row & 7)) * 8));
            }
#pragma unroll
            for (int i = 0; i < 4; ++i)
#pragma unroll
                for (int j = 0; j < 4; ++j)
                    acc[i][j] = __builtin_amdgcn_mfma_f32_16x16x32_bf16(af[i], bfr[j], acc[i][j], 0, 0, 0);
        }
        __syncthreads();
    }
    if (statpart) {
#pragma unroll
        for (int j = 0; j < 4; ++j) {
            float s = 0.f, q = 0.f;
#pragma unroll
            for (int i = 0; i < 4; ++i)
#pragma unroll
                for (int r = 0; r < 4; ++r) {
                    float v = acc[i][j][r];
                    s += v; q += v * v;
                }
            s += __shfl_down(s, 32); s += __shfl_down(s, 16);
            q += __shfl_down(q, 32); q += __shfl_down(q, 16);
            if (lane < 16) {
                Ssum[wr >> 6][wc + j * 16 + l15] = s;
                Ssq[wr >> 6][wc + j * 16 + l15] = q;
            }
        }
        __syncthreads();
        if (t < 128) {
            const size_t bid = (size_t)blockIdx.y * GEMM_BX + blockIdx.x;
            statpart[bid * 256 + t] = Ssum[0][t] + Ssum[1][t];
            statpart[bid * 256 + 128 + t] = Ssq[0][t] + Ssq[1][t];
        }
    }
#pragma unroll
    for (int i = 0; i < 4; ++i) {
#pragma unroll
        for (int r = 0; r < 4; ++r) {
            const int row = rowBase + wr + i * 16 + quad * 4 + r;
            if (row < M) {
#pragma unroll
                for (int j = 0; j < 4; ++j) {
                    const int col = colBase + wc + j * 16 + l15;
                    C[(size_t)row * HDIM + col] = f2bf(acc[i][j][r]);
                }
            }
        }
    }
}

// ---------- fused stat reduce + BN scale/shift: one block per column ----------
__global__ void k_statbn(const float* __restrict__ sp, const float* __restrict__ g,
                         const float* __restrict__ beta, float* __restrict__ sc,
                         float* __restrict__ sh, float invN) {
    const int c = blockIdx.x;
    const size_t base = (size_t)(c >> 7) * GEMM_BX;
    const int off = c & 127;
    float s = 0.f, q = 0.f;
    for (int bx = threadIdx.x; bx < GEMM_BX; bx += 64) {
        s += sp[(base + bx) * 256 + off];
        q += sp[(base + bx) * 256 + 128 + off];
    }
#pragma unroll
    for (int o = 32; o > 0; o >>= 1) { s += __shfl_down(s, o); q += __shfl_down(q, o); }
    if (threadIdx.x == 0) {
        float mu = s * invN;
        float var = q * invN - mu * mu;
        float k = g[c] * rsqrtf(var + 1e-5f);
        sc[c] = k;
        sh[c] = beta[c] - mu * k;
    }
}

// ---------- h_next = relu(C*scale+shift) + identity (+res_b); fp8 copy; optional dot ----------
__global__ __launch_bounds__(256) void k_finalize2(
    const u16* __restrict__ Cb, const u16* __restrict__ iden,
    const float* __restrict__ sc, const float* __restrict__ sh,
    const float* __restrict__ resb, const float* __restrict__ w,
    u16* __restrict__ hout, unsigned char* __restrict__ q8out,
    float* __restrict__ nodedot) {
    const int i = blockIdx.x * 256 + threadIdx.x;
    const size_t base = (size_t)i * 32;
    const int c0 = (i & 7) * 32;
    const uint4* cp = (const uint4*)(Cb + base);
    const uint4* ip = (const uint4*)(iden + base);
    uint4 cv[4], iv[4];
#pragma unroll
    for (int q = 0; q < 4; ++q) cv[q] = cp[q];
#pragma unroll
    for (int q = 0; q < 4; ++q) iv[q] = ip[q];

    float dot = 0.f;
    unsigned int qa[8];
    uint4* op = (uint4*)(hout + base);
#pragma unroll
    for (int q = 0; q < 4; ++q) {
        float cf[8], df[8];
        up8(cv[q], cf); up8(iv[q], df);
        const float4 s0 = ((const float4*)(sc + c0 + q * 8))[0];
        const float4 s1 = ((const float4*)(sc + c0 + q * 8))[1];
        const float4 h0 = ((const float4*)(sh + c0 + q * 8))[0];
        const float4 h1 = ((const float4*)(sh + c0 + q * 8))[1];
        float scf[8] = {s0.x, s0.y, s0.z, s0.w, s1.x, s1.y, s1.z, s1.w};
        float shf[8] = {h0.x, h0.y, h0.z, h0.w, h1.x, h1.y, h1.z, h1.w};
        float rbf[8] = {0.f, 0.f, 0.f, 0.f, 0.f, 0.f, 0.f, 0.f};
        if (resb) {
            const float4 r0 = ((const float4*)(resb + c0 + q * 8))[0];
            const float4 r1 = ((const float4*)(resb + c0 + q * 8))[1];
            rbf[0] = r0.x; rbf[1] = r0.y; rbf[2] = r0.z; rbf[3] = r0.w;
            rbf[4] = r1.x; rbf[5] = r1.y; rbf[6] = r1.z; rbf[7] = r1.w;
        }
        float o[8];
#pragma unroll
        for (int e = 0; e < 8; ++e) {
            float v = cf[e] * scf[e] + shf[e];
            o[e] = fmaxf(v, 0.f) + df[e] + rbf[e];
        }
        if (q8out) {
            unsigned int wlo = __builtin_amdgcn_cvt_pk_fp8_f32(o[0], o[1], 0, false);
            wlo = __builtin_amdgcn_cvt_pk_fp8_f32(o[2], o[3], wlo, true);
            unsigned int whi = __builtin_amdgcn_cvt_pk_fp8_f32(o[4], o[5], 0, false);
            whi = __builtin_amdgcn_cvt_pk_fp8_f32(o[6], o[7], whi, true);
            qa[q * 2] = wlo; qa[q * 2 + 1] = whi;
        }
        if (nodedot) {
            const float4 w0 = ((const float4*)(w + c0 + q * 8))[0];
            const float4 w1 = ((const float4*)(w + c0 + q * 8))[1];
            dot += o[0] * w0.x + o[1] * w0.y + o[2] * w0.z + o[3] * w0.w
                 + o[4] * w1.x + o[5] * w1.y + o[6] * w1.z + o[7] * w1.w;
        }
        op[q] = make_uint4(pk2(o[0], o[1]), pk2(o[2], o[3]), pk2(o[4], o[5]), pk2(o[6], o[7]));
    }
    if (q8out) {
        *(uint4*)(q8out + base) = make_uint4(qa[0], qa[1], qa[2], qa[3]);
        *(uint4*)(q8out + base + 16) = make_uint4(qa[4], qa[5], qa[6], qa[7]);
    }
    if (nodedot) {
        dot += __shfl_down(dot, 4);
        dot += __shfl_down(dot, 2);
        dot += __shfl_down(dot, 1);
        if ((threadIdx.x & 7) == 0) nodedot[i >> 3] = dot;
    }
}

// ---------- readout stage 2: one block per graph, contiguous segment sum ----------
__global__ void k_pool(const float* __restrict__ nodedot, const int* __restrict__ gptr,
                       const float* __restrict__ lb, float* __restrict__ out) {
    const int g = blockIdx.x;
    const int r0 = gptr[g], r1 = gptr[g + 1];
    float s = 0.f;
    for (int i = r0 + threadIdx.x; i < r1; i += 256) s += nodedot[i];
#pragma unroll
    for (int off = 32; off > 0; off >>= 1) s += __shfl_down(s, off);
    __shared__ float red[4];
    const int wave = threadIdx.x >> 6;
    if ((threadIdx.x & 63) == 0) red[wave] = s;
    __syncthreads();
    if (threadIdx.x == 0) {
        float tot = red[0] + red[1] + red[2] + red[3];
        int c = r1 - r0; if (c < 1) c = 1;
        out[g] = tot / (float)c + lb[0];
    }
}

extern "C" void kernel_launch(void* const* d_in, const int* in_sizes, int n_in,
                              void* d_out, int out_size, void* d_ws, size_t ws_size,
                              hipStream_t stream) {
    const float* x     = (const float*)d_in[0];
    const int*   ei    = (const int*)d_in[1];
    const int*   batch = (const int*)d_in[2];
    const float* Wl1 = (const float*)d_in[3];
    const float* Wr1 = (const float*)d_in[5];
    const float* g1  = (const float*)d_in[6];
    const float* be1 = (const float*)d_in[7];
    const float* Wl2 = (const float*)d_in[8];
    const float* Wr2 = (const float*)d_in[10];
    const float* g2  = (const float*)d_in[11];
    const float* be2 = (const float*)d_in[12];
    const float* Wl3 = (const float*)d_in[13];
    const float* Wr3 = (const float*)d_in[15];
    const float* g3  = (const float*)d_in[16];
    const float* be3 = (const float*)d_in[17];
    const float* Wl4 = (const float*)d_in[18];
    const float* Wr4 = (const float*)d_in[20];
    const float* g4  = (const float*)d_in[21];
    const float* be4 = (const float*)d_in[22];
    const float* resW = (const float*)d_in[23];
    const float* resb = (const float*)d_in[24];
    const float* linW = (const float*)d_in[25];
    const float* linb = (const float*)d_in[26];
    float* out = (float*)d_out;

    char* p = (char*)d_ws;
    auto carve = [&](size_t bytes) -> char* {
        char* r = p;
        p += (bytes + 255) & ~(size_t)255;
        return r;
    };
    int*   cptr    = (int*)carve((size_t)(N_NODESC + 1) * 4);
    float* dinv    = (float*)carve((size_t)N_NODESC * 4);
    int*   gptr    = (int*)carve((N_GRAPHSC + 1) * 4);
    float* nodedot = (float*)carve((size_t)N_NODESC * 4);
    float* statpart= (float*)carve((size_t)GEMM_NBLK * 256 * 4);
    float* scale   = (float*)carve(256 * 4);
    float* shift   = (float*)carve(256 * 4);
    int*   bhist   = (int*)carve((size_t)RX_NBLK * RX_NBUCKET * 4);
    int*   btot    = (int*)carve(RX_NBUCKET * 4);
    int*   bex     = (int*)carve((RX_NBUCKET + 1) * 4);
    int*   adj     = (int*)carve((size_t)N_EDGESC * 4);
    u16*   Wt1     = (u16*)carve(256 * 256 * 2);
    u16*   Wt2     = (u16*)carve(256 * 512 * 2);
    u16*   Wt3     = (u16*)carve(256 * 512 * 2);
    u16*   Wt4     = (u16*)carve(256 * 512 * 2);
    u16*   Rt      = (u16*)carve(256 * 128 * 2);
    u16*   xb      = (u16*)carve((size_t)N_NODESC * F_INC * 2);
    u16*   hA      = (u16*)carve((size_t)N_NODESC * HDIM * 2);
    u16*   hB      = (u16*)carve((size_t)N_NODESC * HDIM * 2);
    u16*   agg     = (u16*)carve((size_t)N_NODESC * HDIM * 2);  // aliased as res for layer 1
    u16*   Cb      = (u16*)carve((size_t)N_NODESC * HDIM * 2);
    unsigned char* q8 = (unsigned char*)carve((size_t)N_NODESC * HDIM); // fp8 gather buffer

    // CSR-build temporary aliases buffers dead during the build:
    int2* ebuf = (int2*)Cb;                  // 12.8 MB; dead before layer-1 gemm writes Cb
    unsigned char* xb8 = q8;                 // x fp8 (12.8 MB); dead before finalize(1) overwrites q8

    const int* srcp = ei;
    const int* dstp = ei + N_EDGESC;

    // weight prep + x conversion (bf16 + fp8)
    k_wcat<<<(256 * 256 + 255) / 256, 256, 0, stream>>>(Wl1, Wr1, 128, 128, Wt1);
    k_wcat<<<(256 * 512 + 255) / 256, 256, 0, stream>>>(Wl2, Wr2, 256, 256, Wt2);
    k_wcat<<<(256 * 512 + 255) / 256, 256, 0, stream>>>(Wl3, Wr3, 256, 256, Wt3);
    k_wcat<<<(256 * 512 + 255) / 256, 256, 0, stream>>>(Wl4, Wr4, 256, 256, Wt4);
    k_wcat<<<(256 * 128 + 255) / 256, 256, 0, stream>>>(resW, resW, 128, 0, Rt);
    k_f2both<<<(N_NODESC * F_INC / 8 + 255) / 256, 256, 0, stream>>>(x, xb, xb8, N_NODESC * F_INC / 8);

    // graph structure: bucketed counting sort, LDS atomics only
    k_gfind<<<5, 64, 0, stream>>>(batch, gptr, N_NODESC);
    k_rxcount<<<RX_NBLK, 256, 0, stream>>>(dstp, bhist);
    k_rxscan1<<<RX_NBUCKET, 64, 0, stream>>>(bhist, btot);
    k_rxscan2<<<1, 256, 0, stream>>>(btot, bex, cptr);
    k_rxscatter<<<RX_NBLK, 256, 0, stream>>>(srcp, dstp, bhist, bex, ebuf);
    k_rxcsr<<<RX_NBUCKET, 256, 0, stream>>>(ebuf, bex, cptr, dinv, adj);

    dim3 gGemm(GEMM_BX, 2);
    const float invN = 1.0f / (float)N_NODESC;
    const int finBlocks = N_NODESC * HDIM / 32 / 256;  // 3125, exact

    // ---- layer 1 ----
    k_aggregate4<128><<<25000, 256, 0, stream>>>(xb8, cptr, adj, dinv, agg, N_NODESC);
    k_gemm<<<gGemm, 256, 0, stream>>>(agg, 128, xb, 128, Wt1, Cb, N_NODESC, statpart);
    k_gemm<<<gGemm, 256, 0, stream>>>(xb, 128, xb, 0, Rt, agg, N_NODESC, nullptr);  // res reuses agg
    k_statbn<<<256, 64, 0, stream>>>(statpart, g1, be1, scale, shift, invN);
    k_finalize2<<<finBlocks, 256, 0, stream>>>(Cb, agg, scale, shift, resb, nullptr, hA, q8, nullptr);

    // ---- layer 2 ----
    k_aggregate4<256><<<25000, 256, 0, stream>>>(q8, cptr, adj, dinv, agg, N_NODESC);
    k_gemm<<<gGemm, 256, 0, stream>>>(agg, 256, hA, 256, Wt2, Cb, N_NODESC, statpart);
    k_statbn<<<256, 64, 0, stream>>>(statpart, g2, be2, scale, shift, invN);
    k_finalize2<<<finBlocks, 256, 0, stream>>>(Cb, hA, scale, shift, nullptr, nullptr, hB, q8, nullptr);

    // ---- layer 3 ----
    k_aggregate4<256><<<25000, 256, 0, stream>>>(q8, cptr, adj, dinv, agg, N_NODESC);
    k_gemm<<<gGemm, 256, 0, stream>>>(agg, 256, hB, 256, Wt3, Cb, N_NODESC, statpart);
    k_statbn<<<256, 64, 0, stream>>>(statpart, g3, be3, scale, shift, invN);
    k_finalize2<<<finBlocks, 256, 0, stream>>>(Cb, hB, scale, shift, nullptr, nullptr, hA, q8, nullptr);

    // ---- layer 4 (fused per-node dot with lin_W; no fp8 needed) ----
    k_aggregate4<256><<<25000, 256, 0, stream>>>(q8, cptr, adj, dinv, agg, N_NODESC);
    k_gemm<<<gGemm, 256, 0, stream>>>(agg, 256, hA, 256, Wt4, Cb, N_NODESC, statpart);
    k_statbn<<<256, 64, 0, stream>>>(statpart, g4, be4, scale, shift, invN);
    k_finalize2<<<finBlocks, 256, 0, stream>>>(Cb, hA, scale, shift, nullptr, linW, hB, nullptr, nodedot);

    // ---- pooled mean + lin_b ----
    k_pool<<<N_GRAPHSC, 256, 0, stream>>>(nodedot, gptr, linb, out);
}